// Round 4
// baseline (375.971 us; speedup 1.0000x reference)
//
#include <hip/hip_runtime.h>

#define Bn   64
#define Tn   128
#define NKn  200
#define En   64
#define Ln   40

__device__ __forceinline__ float sigm_f(float x){ return 1.0f/(1.0f+__expf(-x)); }
__device__ __forceinline__ float tanh_f(float x){ float e=__expf(2.0f*x); return 1.0f-2.0f/(e+1.0f); }

// ---------------- both embedding gather-sums in one grid ----------------
__global__ __launch_bounds__(256) void embed_all(const int* __restrict__ sup,
                                                 const int* __restrict__ tgt,
                                                 const float* __restrict__ emb,
                                                 float* __restrict__ sup_enc,
                                                 float* __restrict__ tgt_enc){
  int tid = threadIdx.x;
  int gr  = blockIdx.x*16 + (tid>>4);
  int e4  = tid & 15;
  const int* tr; float* out;
  if (gr < 12800){ tr = sup + (size_t)gr*Ln;        out = sup_enc + (size_t)gr*64; }
  else           { int r2=gr-12800; tr = tgt + (size_t)r2*Ln; out = tgt_enc + (size_t)r2*64; }
  float4 acc = {0.f,0.f,0.f,0.f};
  #pragma unroll 4
  for (int t=0;t<Ln;t++){
    int tok = tr[t];
    float4 v = ((const float4*)emb)[(size_t)tok*16 + e4];
    acc.x+=v.x; acc.y+=v.y; acc.z+=v.z; acc.w+=v.w;
  }
  ((float4*)out)[e4] = acc;
}

// ------- both support GEMMs in ONE pass: thread holds Wa row g AND Wb row g --------
__global__ __launch_bounds__(256,1) void gemm_sup2(const float* __restrict__ x,
                                                   const float* __restrict__ Wa, const float* __restrict__ Wb,
                                                   const float* __restrict__ ba1,const float* __restrict__ ba2,
                                                   const float* __restrict__ bb1,const float* __restrict__ bb2,
                                                   float* __restrict__ outa, float* __restrict__ outb){
  int tid=threadIdx.x, l=tid&63, w=tid>>6;
  int g=tid;
  int m0 = blockIdx.x*16;
  __shared__ __attribute__((aligned(16))) float xs[16*64];
  #pragma unroll
  for(int q=0;q<4;q++){ int r=4*w+q; xs[r*64+l]=x[(size_t)(m0+r)*64+l]; }
  float wa[64], wb[64];
  {
    const float4* A4=(const float4*)(Wa + (size_t)g*64);
    const float4* B4=(const float4*)(Wb + (size_t)g*64);
    #pragma unroll
    for(int q=0;q<16;q++){
      float4 va=A4[q]; wa[4*q]=va.x; wa[4*q+1]=va.y; wa[4*q+2]=va.z; wa[4*q+3]=va.w;
      float4 vb=B4[q]; wb[4*q]=vb.x; wb[4*q+1]=vb.y; wb[4*q+2]=vb.z; wb[4*q+3]=vb.w;
    }
  }
  float biasa=ba1[g]+ba2[g], biasb=bb1[g]+bb2[g];
  __syncthreads();
  #pragma unroll
  for(int r=0;r<16;r++){
    const float4* x4=(const float4*)&xs[r*64];
    float a0=biasa,a1=0.f,b0=biasb,b1=0.f;
    #pragma unroll
    for(int kc=0;kc<16;kc++){
      float4 h4=x4[kc];
      a0=fmaf(wa[4*kc+0],h4.x,a0); b0=fmaf(wb[4*kc+0],h4.x,b0);
      a1=fmaf(wa[4*kc+1],h4.y,a1); b1=fmaf(wb[4*kc+1],h4.y,b1);
      a0=fmaf(wa[4*kc+2],h4.z,a0); b0=fmaf(wb[4*kc+2],h4.z,b0);
      a1=fmaf(wa[4*kc+3],h4.w,a1); b1=fmaf(wb[4*kc+3],h4.w,b1);
    }
    outa[(size_t)(m0+r)*256+g]=a0+a1;
    outb[(size_t)(m0+r)*256+g]=b0+b1;
  }
}

// ---------------- BiLSTM v3: unit-per-wave ownership, no readlane, 1 barrier/step ---------
// R1 lesson: 256 weights/lane overflows the VGPR file. R2 lesson: sched_barrier pins hurt;
// vmcnt drain at __syncthreads was NOT the stall. Theory: the 64 v_readlane->v_fma pairs
// (VALU-writes-SGPR -> VALU-reads-SGPR wait states) + z LDS round-trip were the stall.
// Here: wave ws owns units [16ws,16ws+16); lane l computes z-row (l>>4)*64+16ws+(l&15), so
// all 4 gates of a unit live in lanes l, l+16, l+32, l+48 of ONE wave -> gathered by 3
// independent __shfl_xor (no barrier). h is broadcast via 16x ds_read_b128 of a 64-float
// LDS buffer (uniform addr = free broadcast) into plain VGPR fmas -> no readlane at all.
// Double-buffered h_s -> single __syncthreads per step. out-store after the barrier so its
// vmcnt drain lands a step later. (R3 run died to container infra, not the kernel; resubmit.)
__global__ __launch_bounds__(256,1) void lstm_seq(const float* __restrict__ xg_f,
                                                  const float* __restrict__ xg_b,
                                                  const float* __restrict__ Whh_f,
                                                  const float* __restrict__ Whh_b,
                                                  float* __restrict__ hf,
                                                  float* __restrict__ hb){
  int tid=threadIdx.x, l=tid&63, ws=tid>>6;
  int dir=blockIdx.x>>6, b=blockIdx.x&63;
  const float* xg = dir? xg_b : xg_f;
  const float* Whh= dir? Whh_b: Whh_f;
  float* out = dir? hb : hf;
  int u  = ws*16 + (l&15);            // hidden unit owned (meaningful for l<16)
  int row= (l>>4)*64 + u;             // z-row this lane computes (gate = l>>4)
  float wr[64];
  const float4* W4=(const float4*)(Whh+(size_t)row*64);
  #pragma unroll
  for(int q=0;q<16;q++){ float4 v=W4[q]; wr[4*q]=v.x; wr[4*q+1]=v.y; wr[4*q+2]=v.z; wr[4*q+3]=v.w; }
  __shared__ __attribute__((aligned(16))) float h_s[2][64];
  if (tid<64) h_s[0][tid]=0.f;
  const int tstart = dir?(NKn-1):0, dt = dir?-1:1;
  const float* xgb = xg + (size_t)b*NKn*256 + row;
  float xv = xgb[(size_t)tstart*256];
  float c=0.f;
  __syncthreads();
  for(int s=0;s<NKn;s++){
    int t=tstart+s*dt;
    float xn=0.f;
    if (s<NKn-1) xn = xgb[(size_t)(t+dt)*256];   // prefetch next step's gate pre-act
    const float4* h4=(const float4*)h_s[s&1];    // broadcast reads (uniform addr)
    float a0=0.f,a1=0.f,a2=0.f,a3=0.f;
    #pragma unroll
    for(int q=0;q<16;q++){
      float4 hv=h4[q];
      a0=fmaf(wr[4*q+0],hv.x,a0);
      a1=fmaf(wr[4*q+1],hv.y,a1);
      a2=fmaf(wr[4*q+2],hv.z,a2);
      a3=fmaf(wr[4*q+3],hv.w,a3);
    }
    float z=((a0+a1)+(a2+a3))+xv;
    float zf=__shfl_xor(z,16,64);                // independent shuffles, LDS-pipe pipelined
    float zg=__shfl_xor(z,32,64);
    float zo=__shfl_xor(z,48,64);
    // valid for lanes l<16: (z,zf,zg,zo) = (i,f,g,o) of unit u; other lanes compute unused
    c = sigm_f(zf)*c + sigm_f(z)*tanh_f(zg);
    float h = sigm_f(zo)*tanh_f(c);
    if (l<16) h_s[(s+1)&1][u]=h;
    __syncthreads();                             // nxt-buffer ready; cur reads already done
    if (l<16) out[((size_t)b*NKn+t)*64+u]=h;     // store after barrier: drain hits next step
    xv=xn;
  }
}

// ---------------- zx GEMM (blocks 0..511) + combine/norms (blocks 512..1311) --------------
__global__ __launch_bounds__(256,2) void gemmz_combine(const float* __restrict__ tgt_enc,
                                                       const float* __restrict__ W,
                                                       const float* __restrict__ b1,
                                                       const float* __restrict__ b2,
                                                       float* __restrict__ zx,
                                                       const float* __restrict__ hf,
                                                       const float* __restrict__ hb,
                                                       const float* __restrict__ sup_enc,
                                                       float* __restrict__ semb,
                                                       float* __restrict__ sn){
  int tid=threadIdx.x, l=tid&63, w=tid>>6;
  int blk=blockIdx.x;
  if (blk < 512){
    int g=tid, m0=blk*16;
    __shared__ __attribute__((aligned(16))) float xs[16*64];
    #pragma unroll
    for(int q=0;q<4;q++){ int r=4*w+q; xs[r*64+l]=tgt_enc[(size_t)(m0+r)*64+l]; }
    float wr[64];
    const float4* W4=(const float4*)(W + (size_t)g*64);
    #pragma unroll
    for(int q=0;q<16;q++){ float4 v=W4[q]; wr[4*q]=v.x; wr[4*q+1]=v.y; wr[4*q+2]=v.z; wr[4*q+3]=v.w; }
    float bias=b1[g]+b2[g];
    __syncthreads();
    #pragma unroll
    for(int r=0;r<16;r++){
      const float4* x4=(const float4*)&xs[r*64];
      float a0=bias,a1=0.f,a2=0.f,a3=0.f;
      #pragma unroll
      for(int kc=0;kc<16;kc++){
        float4 h4=x4[kc];
        a0=fmaf(wr[4*kc+0],h4.x,a0);
        a1=fmaf(wr[4*kc+1],h4.y,a1);
        a2=fmaf(wr[4*kc+2],h4.z,a2);
        a3=fmaf(wr[4*kc+3],h4.w,a3);
      }
      zx[(size_t)(m0+r)*256+g]=(a0+a1)+(a2+a3);
    }
  } else {
    int m0=(blk-512)*16;
    #pragma unroll
    for(int q=0;q<4;q++){
      size_t m=(size_t)m0 + w*4 + q;
      float v = hf[m*64+l] + hb[m*64+l] + sup_enc[m*64+l];
      semb[m*64+l]=v;
      float s=v*v;
      #pragma unroll
      for (int o=32;o>0;o>>=1) s += __shfl_xor(s,o,64);
      if (l==0) sn[m]=sqrtf(s);
    }
  }
}

// ------- ALL 5 K-iterations + final cosine softmax in ONE kernel (row-local K loop) -------
// (256,1): ~200 live floats/thread must stay in arch VGPRs -> no spill (R8/R11 lesson:
// do NOT add a zx prologue; zx comes from global).
__global__ __launch_bounds__(256,1) void fused_K(const float* __restrict__ zx,
                                                 const float* __restrict__ Whh,
                                                 const float* __restrict__ x,
                                                 const float* __restrict__ semb,
                                                 const float* __restrict__ sn,
                                                 float* __restrict__ out){
  int tid=threadIdx.x, l=tid&63, w=tid>>6;
  int b=blockIdx.x>>3, t0=(blockIdx.x&7)*16;
  int m0=b*Tn+t0;
  int g=tid;                      // gate index AND support-row index j
  bool valid = g<NKn;
  const float* sbase = semb + (size_t)b*NKn*64;
  __shared__ __attribute__((aligned(16))) float hu_s[16*64];   // 4 KB
  __shared__ __attribute__((aligned(16))) float sbuf[16*256];  // z 16 KB / att[200*20]
  __shared__ __attribute__((aligned(16))) float hn_s[16*64];   // h_next 4 KB
  __shared__ float wredA[64], wredB[64];
  float wr[64], s4f[64];
  {
    const float4* W4=(const float4*)(Whh+(size_t)g*64);
    #pragma unroll
    for(int q=0;q<16;q++){ float4 v=W4[q]; wr[4*q]=v.x; wr[4*q+1]=v.y; wr[4*q+2]=v.z; wr[4*q+3]=v.w; }
  }
  if(valid){
    const float4* sp=(const float4*)(sbase+(size_t)g*64);
    #pragma unroll
    for(int q=0;q<16;q++){ float4 v=sp[q]; s4f[4*q]=v.x; s4f[4*q+1]=v.y; s4f[4*q+2]=v.z; s4f[4*q+3]=v.w; }
  } else {
    #pragma unroll
    for(int q=0;q<64;q++) s4f[q]=0.f;
  }
  float zxr[16];
  #pragma unroll
  for(int r=0;r<16;r++) zxr[r]=zx[(size_t)(m0+r)*256+g];
  float xr[4];
  #pragma unroll
  for(int q=0;q<4;q++) xr[q]=x[(size_t)(m0+q*4+w)*64+l];
  float snr = valid ? sn[(size_t)b*NKn+g] : 1.f;
  float cq[4]={0.f,0.f,0.f,0.f};
  float scr[16], ex[16], mx[16];
  for(int k=0;k<5;k++){
    if(k==0){
      #pragma unroll
      for(int r=0;r<16;r++){ sbuf[r*256+g]=zxr[r]; scr[r]=0.f; }
    } else {
      #pragma unroll
      for(int r=0;r<16;r++){
        float z0=zxr[r], z1=0.f, sc0=0.f, sc1=0.f;
        const float4* h4p=(const float4*)&hu_s[r*64];
        #pragma unroll
        for(int kc=0;kc<16;kc++){
          float4 h4=h4p[kc];
          z0 =fmaf(wr[4*kc+0] ,h4.x,z0 ); sc0=fmaf(s4f[4*kc+0],h4.x,sc0);
          z1 =fmaf(wr[4*kc+1] ,h4.y,z1 ); sc1=fmaf(s4f[4*kc+1],h4.y,sc1);
          z0 =fmaf(wr[4*kc+2] ,h4.z,z0 ); sc0=fmaf(s4f[4*kc+2],h4.z,sc0);
          z1 =fmaf(wr[4*kc+3] ,h4.w,z1 ); sc1=fmaf(s4f[4*kc+3],h4.w,sc1);
        }
        sbuf[r*256+g]=z0+z1;
        scr[r]=sc0+sc1;
      }
    }
    __syncthreads();                               // B1: z ready (hu_s reads done)
    #pragma unroll
    for(int q=0;q<4;q++){
      int r=q*4+w;
      float zi=sbuf[r*256+l], zf=sbuf[r*256+64+l], zg=sbuf[r*256+128+l], zo=sbuf[r*256+192+l];
      float c=sigm_f(zf)*cq[q]+sigm_f(zi)*tanh_f(zg);
      cq[q]=c;
      hn_s[r*64+l]=sigm_f(zo)*tanh_f(c)+xr[q];
    }
    if(k<4){
      #pragma unroll
      for(int t=0;t<16;t++){
        float m = valid ? scr[t] : -1e30f;
        #pragma unroll
        for(int o=32;o>0;o>>=1) m=fmaxf(m,__shfl_xor(m,o,64));
        mx[t]=m;
      }
      if(l==0){
        #pragma unroll
        for(int t=0;t<16;t++) wredA[t*4+w]=mx[t];
      }
      __syncthreads();                             // B2: z reads done; wredA ready
      #pragma unroll
      for(int t=0;t<16;t++){
        const float4 m4=*(const float4*)&wredA[t*4];
        float gm=fmaxf(fmaxf(m4.x,m4.y),fmaxf(m4.z,m4.w));
        float e=valid?__expf(scr[t]-gm):0.f;
        ex[t]=e;
        float s=e;
        #pragma unroll
        for(int o=32;o>0;o>>=1) s+=__shfl_xor(s,o,64);
        mx[t]=s;
      }
      if(l==0){
        #pragma unroll
        for(int t=0;t<16;t++) wredB[t*4+w]=mx[t];
      }
      __syncthreads();                             // B3: wredB ready
      #pragma unroll
      for(int t=0;t<16;t++){
        const float4 s4v=*(const float4*)&wredB[t*4];
        float tot=(s4v.x+s4v.y)+(s4v.z+s4v.w);
        ex[t]*=1.0f/tot;                           // att
      }
      if(valid){
        #pragma unroll
        for(int cg=0;cg<4;cg++)
          *(float4*)&sbuf[g*20+4*cg]=make_float4(ex[4*cg+0],ex[4*cg+1],ex[4*cg+2],ex[4*cg+3]);
      }
      __syncthreads();                             // B4: att + hn_s visible
      float r0=0.f,r1=0.f,r2=0.f,r3=0.f;
      #pragma unroll 8
      for(int j=0;j<NKn;j++){
        float4 a4=*(const float4*)&sbuf[j*20+w*4];
        float sv=sbase[(size_t)j*64+l];            // L2-resident, coalesced (VMEM pipe)
        r0=fmaf(a4.x,sv,r0);
        r1=fmaf(a4.y,sv,r1);
        r2=fmaf(a4.z,sv,r2);
        r3=fmaf(a4.w,sv,r3);
      }
      int rb=w*4;
      hu_s[(rb+0)*64+l]=r0 + hn_s[(rb+0)*64+l];
      hu_s[(rb+1)*64+l]=r1 + hn_s[(rb+1)*64+l];
      hu_s[(rb+2)*64+l]=r2 + hn_s[(rb+2)*64+l];
      hu_s[(rb+3)*64+l]=r3 + hn_s[(rb+3)*64+l];
      __syncthreads();                             // B5: hu ready for next iteration
    }
  }
  __syncthreads();                                 // hn_s complete
  float tnorm[16];
  #pragma unroll
  for(int t=0;t<16;t++){
    float v=hn_s[t*64+l];
    float s=v*v;
    #pragma unroll
    for(int o=32;o>0;o>>=1) s+=__shfl_xor(s,o,64);
    tnorm[t]=sqrtf(s);
  }
  #pragma unroll
  for(int t=0;t<16;t++){
    const float4* h4p=(const float4*)&hn_s[t*64];
    float a0=0.f,a1=0.f;
    #pragma unroll
    for(int kc=0;kc<16;kc++){
      float4 h4=h4p[kc];
      a0=fmaf(s4f[4*kc+0],h4.x,a0);
      a1=fmaf(s4f[4*kc+1],h4.y,a1);
      a0=fmaf(s4f[4*kc+2],h4.z,a0);
      a1=fmaf(s4f[4*kc+3],h4.w,a1);
    }
    scr[t]=(a0+a1) / fmaxf(tnorm[t]*snr,1e-8f);
  }
  #pragma unroll
  for(int t=0;t<16;t++){
    float m = valid ? scr[t] : -1e30f;
    #pragma unroll
    for(int o=32;o>0;o>>=1) m=fmaxf(m,__shfl_xor(m,o,64));
    mx[t]=m;
  }
  if(l==0){
    #pragma unroll
    for(int t=0;t<16;t++) wredA[t*4+w]=mx[t];
  }
  __syncthreads();
  #pragma unroll
  for(int t=0;t<16;t++){
    const float4 m4=*(const float4*)&wredA[t*4];
    float gm=fmaxf(fmaxf(m4.x,m4.y),fmaxf(m4.z,m4.w));
    float e=valid?__expf(scr[t]-gm):0.f;
    ex[t]=e;
    float s=e;
    #pragma unroll
    for(int o=32;o>0;o>>=1) s+=__shfl_xor(s,o,64);
    mx[t]=s;
  }
  if(l==0){
    #pragma unroll
    for(int t=0;t<16;t++) wredB[t*4+w]=mx[t];
  }
  __syncthreads();
  #pragma unroll
  for(int t=0;t<16;t++){
    const float4 s4v=*(const float4*)&wredB[t*4];
    float tot=(s4v.x+s4v.y)+(s4v.z+s4v.w);
    if(valid) out[((size_t)(m0+t))*NKn + g]=ex[t]*(1.0f/tot);
  }
}

extern "C" void kernel_launch(void* const* d_in, const int* in_sizes, int n_in,
                              void* d_out, int out_size, void* d_ws, size_t ws_size,
                              hipStream_t stream) {
  (void)in_sizes; (void)n_in; (void)out_size; (void)ws_size;
  const int*   sup_toks = (const int*)d_in[0];
  const int*   tgt_toks = (const int*)d_in[1];
  const float* emb      = (const float*)d_in[2];
  const float* f_Wih    = (const float*)d_in[3];
  const float* f_Whh    = (const float*)d_in[4];
  const float* f_bih    = (const float*)d_in[5];
  const float* f_bhh    = (const float*)d_in[6];
  const float* gf_Wih   = (const float*)d_in[7];
  const float* gf_Whh   = (const float*)d_in[8];
  const float* gf_bih   = (const float*)d_in[9];
  const float* gf_bhh   = (const float*)d_in[10];
  const float* gb_Wih   = (const float*)d_in[11];
  const float* gb_Whh   = (const float*)d_in[12];
  const float* gb_bih   = (const float*)d_in[13];
  const float* gb_bhh   = (const float*)d_in[14];

  float* ws = (float*)d_ws;
  float* sup_enc = ws;                         // 819200
  float* tgt_enc = sup_enc + 819200;           // 524288
  float* bufA    = tgt_enc + 524288;           // 3276800 : xg_f, later zx
  float* bufB    = bufA    + 3276800;          // 3276800 : xg_b
  float* semb    = bufB    + 3276800;          // 819200  : hf, then sup_emb
  float* hb      = semb    + 819200;           // 819200
  float* sn      = hb      + 819200;           // 12800

  float* xg_f = bufA;
  float* xg_b = bufB;

  embed_all<<<1312,256,0,stream>>>(sup_toks, tgt_toks, emb, sup_enc, tgt_enc);
  gemm_sup2<<<800,256,0,stream>>>(sup_enc, gf_Wih, gb_Wih,
                                  gf_bih, gf_bhh, gb_bih, gb_bhh, xg_f, xg_b);
  lstm_seq<<<128,256,0,stream>>>(xg_f, xg_b, gf_Whh, gb_Whh, semb /*hf*/, hb);

  float* zx = bufA;                    // xg_f dead after lstm

  gemmz_combine<<<1312,256,0,stream>>>(tgt_enc, f_Wih, f_bih, f_bhh, zx,
                                       semb, hb, sup_enc, semb, sn);

  fused_K<<<512,256,0,stream>>>(zx, f_Whh, tgt_enc, semb, sn, (float*)d_out);
}

// Round 5
// 366.958 us; speedup vs baseline: 1.0246x; 1.0246x over previous
//
#include <hip/hip_runtime.h>

#define Bn   64
#define Tn   128
#define NKn  200
#define En   64
#define Ln   40

__device__ __forceinline__ float sigm_f(float x){ return 1.0f/(1.0f+__expf(-x)); }
__device__ __forceinline__ float tanh_f(float x){ float e=__expf(2.0f*x); return 1.0f-2.0f/(e+1.0f); }
__device__ __forceinline__ float rdl(float v, int ln){
  return __uint_as_float(__builtin_amdgcn_readlane(__float_as_uint(v), (unsigned)ln));
}

// ---------------- both embedding gather-sums in one grid ----------------
__global__ __launch_bounds__(256) void embed_all(const int* __restrict__ sup,
                                                 const int* __restrict__ tgt,
                                                 const float* __restrict__ emb,
                                                 float* __restrict__ sup_enc,
                                                 float* __restrict__ tgt_enc){
  int tid = threadIdx.x;
  int gr  = blockIdx.x*16 + (tid>>4);
  int e4  = tid & 15;
  const int* tr; float* out;
  if (gr < 12800){ tr = sup + (size_t)gr*Ln;        out = sup_enc + (size_t)gr*64; }
  else           { int r2=gr-12800; tr = tgt + (size_t)r2*Ln; out = tgt_enc + (size_t)r2*64; }
  float4 acc = {0.f,0.f,0.f,0.f};
  #pragma unroll 4
  for (int t=0;t<Ln;t++){
    int tok = tr[t];
    float4 v = ((const float4*)emb)[(size_t)tok*16 + e4];
    acc.x+=v.x; acc.y+=v.y; acc.z+=v.z; acc.w+=v.w;
  }
  ((float4*)out)[e4] = acc;
}

// ------- both support GEMMs in ONE pass: thread holds Wa row g AND Wb row g --------
__global__ __launch_bounds__(256,1) void gemm_sup2(const float* __restrict__ x,
                                                   const float* __restrict__ Wa, const float* __restrict__ Wb,
                                                   const float* __restrict__ ba1,const float* __restrict__ ba2,
                                                   const float* __restrict__ bb1,const float* __restrict__ bb2,
                                                   float* __restrict__ outa, float* __restrict__ outb){
  int tid=threadIdx.x, l=tid&63, w=tid>>6;
  int g=tid;
  int m0 = blockIdx.x*16;
  __shared__ __attribute__((aligned(16))) float xs[16*64];
  #pragma unroll
  for(int q=0;q<4;q++){ int r=4*w+q; xs[r*64+l]=x[(size_t)(m0+r)*64+l]; }
  float wa[64], wb[64];
  {
    const float4* A4=(const float4*)(Wa + (size_t)g*64);
    const float4* B4=(const float4*)(Wb + (size_t)g*64);
    #pragma unroll
    for(int q=0;q<16;q++){
      float4 va=A4[q]; wa[4*q]=va.x; wa[4*q+1]=va.y; wa[4*q+2]=va.z; wa[4*q+3]=va.w;
      float4 vb=B4[q]; wb[4*q]=vb.x; wb[4*q+1]=vb.y; wb[4*q+2]=vb.z; wb[4*q+3]=vb.w;
    }
  }
  float biasa=ba1[g]+ba2[g], biasb=bb1[g]+bb2[g];
  __syncthreads();
  #pragma unroll
  for(int r=0;r<16;r++){
    const float4* x4=(const float4*)&xs[r*64];
    float a0=biasa,a1=0.f,b0=biasb,b1=0.f;
    #pragma unroll
    for(int kc=0;kc<16;kc++){
      float4 h4=x4[kc];
      a0=fmaf(wa[4*kc+0],h4.x,a0); b0=fmaf(wb[4*kc+0],h4.x,b0);
      a1=fmaf(wa[4*kc+1],h4.y,a1); b1=fmaf(wb[4*kc+1],h4.y,b1);
      a0=fmaf(wa[4*kc+2],h4.z,a0); b0=fmaf(wb[4*kc+2],h4.z,b0);
      a1=fmaf(wa[4*kc+3],h4.w,a1); b1=fmaf(wb[4*kc+3],h4.w,b1);
    }
    outa[(size_t)(m0+r)*256+g]=a0+a1;
    outb[(size_t)(m0+r)*256+g]=b0+b1;
  }
}

// ---------------- BiLSTM v4: R0 structure + lgkm-only barrier + b128 z-read ----------------
// R0 (112.7us) is the best structure: 4 waves, readlane matvec, redundant c/h per wave.
// R1 (1-wave, 256 wts) = VGPR bust. R2 (lgkm barrier + sched_barrier pins) regressed -> blame
// the pins (m141), not the barrier. v3 (unit-per-wave) lengthened the serial tail.
// V4 = R0 with exactly three cuts, no pins, no restructure:
//  1) single-asm "s_waitcnt lgkmcnt(0); s_barrier" ("memory" clobber): out-store and xg
//     prefetch never vmcnt-drain on the critical path (__syncthreads would drain both).
//  2) z exchange transposed: wave w writes z_s[buf][l*4+w] (8-way write conflict, 1 op,
//     negligible) so read-back is ONE ds_read_b128 per lane instead of 4 strided b32.
//  3) prefetch distance 2 (vmcnt never force-drained; ~2 steps of slack for L3/HBM).
__global__ __launch_bounds__(256,1) void lstm_seq(const float* __restrict__ xg_f,
                                                  const float* __restrict__ xg_b,
                                                  const float* __restrict__ Whh_f,
                                                  const float* __restrict__ Whh_b,
                                                  float* __restrict__ hf,
                                                  float* __restrict__ hb){
  int tid=threadIdx.x, l=tid&63, w=tid>>6;
  int dir=blockIdx.x>>6, b=blockIdx.x&63;
  const float* xg = dir? xg_b : xg_f;
  const float* Whh= dir? Whh_b: Whh_f;
  float* out = dir? hb : hf;
  float wr[64];
  const float4* W4=(const float4*)(Whh+(size_t)(w*64+l)*64);
  #pragma unroll
  for(int q=0;q<16;q++){ float4 v=W4[q]; wr[4*q]=v.x; wr[4*q+1]=v.y; wr[4*q+2]=v.z; wr[4*q+3]=v.w; }
  __shared__ __attribute__((aligned(16))) float z_s[2][256];   // [buf][unit*4 + gate]
  float h=0.f, c=0.f;
  const int tstart = dir?(NKn-1):0, dt = dir?-1:1;
  const float* xgb = xg + (size_t)b*NKn*256 + w*64 + l;
  float xv  = xgb[(size_t)tstart*256];
  float xn1 = xgb[(size_t)(tstart+dt)*256];
  for(int s=0;s<NKn;s++){
    int t=tstart+s*dt;
    float xn2=0.f;
    if (s<NKn-2) xn2 = xgb[(size_t)(t+2*dt)*256];   // distance-2 prefetch, stays in flight
    float a0=xv,a1=0.f,a2=0.f,a3=0.f;
    #pragma unroll
    for(int q=0;q<16;q++){
      a0=fmaf(wr[4*q+0],rdl(h,4*q+0),a0);
      a1=fmaf(wr[4*q+1],rdl(h,4*q+1),a1);
      a2=fmaf(wr[4*q+2],rdl(h,4*q+2),a2);
      a3=fmaf(wr[4*q+3],rdl(h,4*q+3),a3);
    }
    z_s[s&1][l*4+w]=(a0+a1)+(a2+a3);
    // lgkm-only barrier: LDS z-exchange ordered; vmcnt traffic sails through.
    asm volatile("s_waitcnt lgkmcnt(0)\n\ts_barrier" ::: "memory");
    const float4 z4 = *(const float4*)&z_s[s&1][l*4];   // one b128: zi,zf,zg,zo
    c = sigm_f(z4.y)*c + sigm_f(z4.x)*tanh_f(z4.z);     // redundant per wave; h stays in regs
    h = sigm_f(z4.w)*tanh_f(c);
    if(w==0) out[((size_t)b*NKn+t)*64+l]=h;
    xv=xn1; xn1=xn2;
  }
}

// ---------------- zx GEMM (blocks 0..511) + combine/norms (blocks 512..1311) --------------
__global__ __launch_bounds__(256,2) void gemmz_combine(const float* __restrict__ tgt_enc,
                                                       const float* __restrict__ W,
                                                       const float* __restrict__ b1,
                                                       const float* __restrict__ b2,
                                                       float* __restrict__ zx,
                                                       const float* __restrict__ hf,
                                                       const float* __restrict__ hb,
                                                       const float* __restrict__ sup_enc,
                                                       float* __restrict__ semb,
                                                       float* __restrict__ sn){
  int tid=threadIdx.x, l=tid&63, w=tid>>6;
  int blk=blockIdx.x;
  if (blk < 512){
    int g=tid, m0=blk*16;
    __shared__ __attribute__((aligned(16))) float xs[16*64];
    #pragma unroll
    for(int q=0;q<4;q++){ int r=4*w+q; xs[r*64+l]=tgt_enc[(size_t)(m0+r)*64+l]; }
    float wr[64];
    const float4* W4=(const float4*)(W + (size_t)g*64);
    #pragma unroll
    for(int q=0;q<16;q++){ float4 v=W4[q]; wr[4*q]=v.x; wr[4*q+1]=v.y; wr[4*q+2]=v.z; wr[4*q+3]=v.w; }
    float bias=b1[g]+b2[g];
    __syncthreads();
    #pragma unroll
    for(int r=0;r<16;r++){
      const float4* x4=(const float4*)&xs[r*64];
      float a0=bias,a1=0.f,a2=0.f,a3=0.f;
      #pragma unroll
      for(int kc=0;kc<16;kc++){
        float4 h4=x4[kc];
        a0=fmaf(wr[4*kc+0],h4.x,a0);
        a1=fmaf(wr[4*kc+1],h4.y,a1);
        a2=fmaf(wr[4*kc+2],h4.z,a2);
        a3=fmaf(wr[4*kc+3],h4.w,a3);
      }
      zx[(size_t)(m0+r)*256+g]=(a0+a1)+(a2+a3);
    }
  } else {
    int m0=(blk-512)*16;
    #pragma unroll
    for(int q=0;q<4;q++){
      size_t m=(size_t)m0 + w*4 + q;
      float v = hf[m*64+l] + hb[m*64+l] + sup_enc[m*64+l];
      semb[m*64+l]=v;
      float s=v*v;
      #pragma unroll
      for (int o=32;o>0;o>>=1) s += __shfl_xor(s,o,64);
      if (l==0) sn[m]=sqrtf(s);
    }
  }
}

// ------- ALL 5 K-iterations + final cosine softmax in ONE kernel (row-local K loop) -------
// (256,1): ~200 live floats/thread must stay in arch VGPRs -> no spill (R8/R11 lesson:
// do NOT add a zx prologue; zx comes from global).
__global__ __launch_bounds__(256,1) void fused_K(const float* __restrict__ zx,
                                                 const float* __restrict__ Whh,
                                                 const float* __restrict__ x,
                                                 const float* __restrict__ semb,
                                                 const float* __restrict__ sn,
                                                 float* __restrict__ out){
  int tid=threadIdx.x, l=tid&63, w=tid>>6;
  int b=blockIdx.x>>3, t0=(blockIdx.x&7)*16;
  int m0=b*Tn+t0;
  int g=tid;                      // gate index AND support-row index j
  bool valid = g<NKn;
  const float* sbase = semb + (size_t)b*NKn*64;
  __shared__ __attribute__((aligned(16))) float hu_s[16*64];   // 4 KB
  __shared__ __attribute__((aligned(16))) float sbuf[16*256];  // z 16 KB / att[200*20]
  __shared__ __attribute__((aligned(16))) float hn_s[16*64];   // h_next 4 KB
  __shared__ float wredA[64], wredB[64];
  float wr[64], s4f[64];
  {
    const float4* W4=(const float4*)(Whh+(size_t)g*64);
    #pragma unroll
    for(int q=0;q<16;q++){ float4 v=W4[q]; wr[4*q]=v.x; wr[4*q+1]=v.y; wr[4*q+2]=v.z; wr[4*q+3]=v.w; }
  }
  if(valid){
    const float4* sp=(const float4*)(sbase+(size_t)g*64);
    #pragma unroll
    for(int q=0;q<16;q++){ float4 v=sp[q]; s4f[4*q]=v.x; s4f[4*q+1]=v.y; s4f[4*q+2]=v.z; s4f[4*q+3]=v.w; }
  } else {
    #pragma unroll
    for(int q=0;q<64;q++) s4f[q]=0.f;
  }
  float zxr[16];
  #pragma unroll
  for(int r=0;r<16;r++) zxr[r]=zx[(size_t)(m0+r)*256+g];
  float xr[4];
  #pragma unroll
  for(int q=0;q<4;q++) xr[q]=x[(size_t)(m0+q*4+w)*64+l];
  float snr = valid ? sn[(size_t)b*NKn+g] : 1.f;
  float cq[4]={0.f,0.f,0.f,0.f};
  float scr[16], ex[16], mx[16];
  for(int k=0;k<5;k++){
    if(k==0){
      #pragma unroll
      for(int r=0;r<16;r++){ sbuf[r*256+g]=zxr[r]; scr[r]=0.f; }
    } else {
      #pragma unroll
      for(int r=0;r<16;r++){
        float z0=zxr[r], z1=0.f, sc0=0.f, sc1=0.f;
        const float4* h4p=(const float4*)&hu_s[r*64];
        #pragma unroll
        for(int kc=0;kc<16;kc++){
          float4 h4=h4p[kc];
          z0 =fmaf(wr[4*kc+0] ,h4.x,z0 ); sc0=fmaf(s4f[4*kc+0],h4.x,sc0);
          z1 =fmaf(wr[4*kc+1] ,h4.y,z1 ); sc1=fmaf(s4f[4*kc+1],h4.y,sc1);
          z0 =fmaf(wr[4*kc+2] ,h4.z,z0 ); sc0=fmaf(s4f[4*kc+2],h4.z,sc0);
          z1 =fmaf(wr[4*kc+3] ,h4.w,z1 ); sc1=fmaf(s4f[4*kc+3],h4.w,sc1);
        }
        sbuf[r*256+g]=z0+z1;
        scr[r]=sc0+sc1;
      }
    }
    __syncthreads();                               // B1: z ready (hu_s reads done)
    #pragma unroll
    for(int q=0;q<4;q++){
      int r=q*4+w;
      float zi=sbuf[r*256+l], zf=sbuf[r*256+64+l], zg=sbuf[r*256+128+l], zo=sbuf[r*256+192+l];
      float c=sigm_f(zf)*cq[q]+sigm_f(zi)*tanh_f(zg);
      cq[q]=c;
      hn_s[r*64+l]=sigm_f(zo)*tanh_f(c)+xr[q];
    }
    if(k<4){
      #pragma unroll
      for(int t=0;t<16;t++){
        float m = valid ? scr[t] : -1e30f;
        #pragma unroll
        for(int o=32;o>0;o>>=1) m=fmaxf(m,__shfl_xor(m,o,64));
        mx[t]=m;
      }
      if(l==0){
        #pragma unroll
        for(int t=0;t<16;t++) wredA[t*4+w]=mx[t];
      }
      __syncthreads();                             // B2: z reads done; wredA ready
      #pragma unroll
      for(int t=0;t<16;t++){
        const float4 m4=*(const float4*)&wredA[t*4];
        float gm=fmaxf(fmaxf(m4.x,m4.y),fmaxf(m4.z,m4.w));
        float e=valid?__expf(scr[t]-gm):0.f;
        ex[t]=e;
        float s=e;
        #pragma unroll
        for(int o=32;o>0;o>>=1) s+=__shfl_xor(s,o,64);
        mx[t]=s;
      }
      if(l==0){
        #pragma unroll
        for(int t=0;t<16;t++) wredB[t*4+w]=mx[t];
      }
      __syncthreads();                             // B3: wredB ready
      #pragma unroll
      for(int t=0;t<16;t++){
        const float4 s4v=*(const float4*)&wredB[t*4];
        float tot=(s4v.x+s4v.y)+(s4v.z+s4v.w);
        ex[t]*=1.0f/tot;                           // att
      }
      if(valid){
        #pragma unroll
        for(int cg=0;cg<4;cg++)
          *(float4*)&sbuf[g*20+4*cg]=make_float4(ex[4*cg+0],ex[4*cg+1],ex[4*cg+2],ex[4*cg+3]);
      }
      __syncthreads();                             // B4: att + hn_s visible
      float r0=0.f,r1=0.f,r2=0.f,r3=0.f;
      #pragma unroll 8
      for(int j=0;j<NKn;j++){
        float4 a4=*(const float4*)&sbuf[j*20+w*4];
        float sv=sbase[(size_t)j*64+l];            // L2-resident, coalesced (VMEM pipe)
        r0=fmaf(a4.x,sv,r0);
        r1=fmaf(a4.y,sv,r1);
        r2=fmaf(a4.z,sv,r2);
        r3=fmaf(a4.w,sv,r3);
      }
      int rb=w*4;
      hu_s[(rb+0)*64+l]=r0 + hn_s[(rb+0)*64+l];
      hu_s[(rb+1)*64+l]=r1 + hn_s[(rb+1)*64+l];
      hu_s[(rb+2)*64+l]=r2 + hn_s[(rb+2)*64+l];
      hu_s[(rb+3)*64+l]=r3 + hn_s[(rb+3)*64+l];
      __syncthreads();                             // B5: hu ready for next iteration
    }
  }
  __syncthreads();                                 // hn_s complete
  float tnorm[16];
  #pragma unroll
  for(int t=0;t<16;t++){
    float v=hn_s[t*64+l];
    float s=v*v;
    #pragma unroll
    for(int o=32;o>0;o>>=1) s+=__shfl_xor(s,o,64);
    tnorm[t]=sqrtf(s);
  }
  #pragma unroll
  for(int t=0;t<16;t++){
    const float4* h4p=(const float4*)&hn_s[t*64];
    float a0=0.f,a1=0.f;
    #pragma unroll
    for(int kc=0;kc<16;kc++){
      float4 h4=h4p[kc];
      a0=fmaf(s4f[4*kc+0],h4.x,a0);
      a1=fmaf(s4f[4*kc+1],h4.y,a1);
      a0=fmaf(s4f[4*kc+2],h4.z,a0);
      a1=fmaf(s4f[4*kc+3],h4.w,a1);
    }
    scr[t]=(a0+a1) / fmaxf(tnorm[t]*snr,1e-8f);
  }
  #pragma unroll
  for(int t=0;t<16;t++){
    float m = valid ? scr[t] : -1e30f;
    #pragma unroll
    for(int o=32;o>0;o>>=1) m=fmaxf(m,__shfl_xor(m,o,64));
    mx[t]=m;
  }
  if(l==0){
    #pragma unroll
    for(int t=0;t<16;t++) wredA[t*4+w]=mx[t];
  }
  __syncthreads();
  #pragma unroll
  for(int t=0;t<16;t++){
    const float4 m4=*(const float4*)&wredA[t*4];
    float gm=fmaxf(fmaxf(m4.x,m4.y),fmaxf(m4.z,m4.w));
    float e=valid?__expf(scr[t]-gm):0.f;
    ex[t]=e;
    float s=e;
    #pragma unroll
    for(int o=32;o>0;o>>=1) s+=__shfl_xor(s,o,64);
    mx[t]=s;
  }
  if(l==0){
    #pragma unroll
    for(int t=0;t<16;t++) wredB[t*4+w]=mx[t];
  }
  __syncthreads();
  #pragma unroll
  for(int t=0;t<16;t++){
    const float4 s4v=*(const float4*)&wredB[t*4];
    float tot=(s4v.x+s4v.y)+(s4v.z+s4v.w);
    if(valid) out[((size_t)(m0+t))*NKn + g]=ex[t]*(1.0f/tot);
  }
}

extern "C" void kernel_launch(void* const* d_in, const int* in_sizes, int n_in,
                              void* d_out, int out_size, void* d_ws, size_t ws_size,
                              hipStream_t stream) {
  (void)in_sizes; (void)n_in; (void)out_size; (void)ws_size;
  const int*   sup_toks = (const int*)d_in[0];
  const int*   tgt_toks = (const int*)d_in[1];
  const float* emb      = (const float*)d_in[2];
  const float* f_Wih    = (const float*)d_in[3];
  const float* f_Whh    = (const float*)d_in[4];
  const float* f_bih    = (const float*)d_in[5];
  const float* f_bhh    = (const float*)d_in[6];
  const float* gf_Wih   = (const float*)d_in[7];
  const float* gf_Whh   = (const float*)d_in[8];
  const float* gf_bih   = (const float*)d_in[9];
  const float* gf_bhh   = (const float*)d_in[10];
  const float* gb_Wih   = (const float*)d_in[11];
  const float* gb_Whh   = (const float*)d_in[12];
  const float* gb_bih   = (const float*)d_in[13];
  const float* gb_bhh   = (const float*)d_in[14];

  float* ws = (float*)d_ws;
  float* sup_enc = ws;                         // 819200
  float* tgt_enc = sup_enc + 819200;           // 524288
  float* bufA    = tgt_enc + 524288;           // 3276800 : xg_f, later zx
  float* bufB    = bufA    + 3276800;          // 3276800 : xg_b
  float* semb    = bufB    + 3276800;          // 819200  : hf, then sup_emb
  float* hb      = semb    + 819200;           // 819200
  float* sn      = hb      + 819200;           // 12800

  float* xg_f = bufA;
  float* xg_b = bufB;

  embed_all<<<1312,256,0,stream>>>(sup_toks, tgt_toks, emb, sup_enc, tgt_enc);
  gemm_sup2<<<800,256,0,stream>>>(sup_enc, gf_Wih, gb_Wih,
                                  gf_bih, gf_bhh, gb_bih, gb_bhh, xg_f, xg_b);
  lstm_seq<<<128,256,0,stream>>>(xg_f, xg_b, gf_Whh, gb_Whh, semb /*hf*/, hb);

  float* zx = bufA;                    // xg_f dead after lstm

  gemmz_combine<<<1312,256,0,stream>>>(tgt_enc, f_Wih, f_bih, f_bhh, zx,
                                       semb, hb, sup_enc, semb, sn);

  fused_K<<<512,256,0,stream>>>(zx, f_Whh, tgt_enc, semb, sn, (float*)d_out);
}

// Round 6
// 359.696 us; speedup vs baseline: 1.0452x; 1.0202x over previous
//
#include <hip/hip_runtime.h>

#define Bn   64
#define Tn   128
#define NKn  200
#define En   64
#define Ln   40

__device__ __forceinline__ float sigm_f(float x){ return 1.0f/(1.0f+__expf(-x)); }
__device__ __forceinline__ float tanh_f(float x){ float e=__expf(2.0f*x); return 1.0f-2.0f/(e+1.0f); }
__device__ __forceinline__ float rdl(float v, int ln){
  return __uint_as_float(__builtin_amdgcn_readlane(__float_as_uint(v), (unsigned)ln));
}

// ---------------- both embedding gather-sums in one grid ----------------
__global__ __launch_bounds__(256) void embed_all(const int* __restrict__ sup,
                                                 const int* __restrict__ tgt,
                                                 const float* __restrict__ emb,
                                                 float* __restrict__ sup_enc,
                                                 float* __restrict__ tgt_enc){
  int tid = threadIdx.x;
  int gr  = blockIdx.x*16 + (tid>>4);
  int e4  = tid & 15;
  const int* tr; float* out;
  if (gr < 12800){ tr = sup + (size_t)gr*Ln;        out = sup_enc + (size_t)gr*64; }
  else           { int r2=gr-12800; tr = tgt + (size_t)r2*Ln; out = tgt_enc + (size_t)r2*64; }
  float4 acc = {0.f,0.f,0.f,0.f};
  #pragma unroll 4
  for (int t=0;t<Ln;t++){
    int tok = tr[t];
    float4 v = ((const float4*)emb)[(size_t)tok*16 + e4];
    acc.x+=v.x; acc.y+=v.y; acc.z+=v.z; acc.w+=v.w;
  }
  ((float4*)out)[e4] = acc;
}

// ------- both support GEMMs in ONE pass: thread holds Wa row g AND Wb row g --------
__global__ __launch_bounds__(256,1) void gemm_sup2(const float* __restrict__ x,
                                                   const float* __restrict__ Wa, const float* __restrict__ Wb,
                                                   const float* __restrict__ ba1,const float* __restrict__ ba2,
                                                   const float* __restrict__ bb1,const float* __restrict__ bb2,
                                                   float* __restrict__ outa, float* __restrict__ outb){
  int tid=threadIdx.x, l=tid&63, w=tid>>6;
  int g=tid;
  int m0 = blockIdx.x*16;
  __shared__ __attribute__((aligned(16))) float xs[16*64];
  #pragma unroll
  for(int q=0;q<4;q++){ int r=4*w+q; xs[r*64+l]=x[(size_t)(m0+r)*64+l]; }
  float wa[64], wb[64];
  {
    const float4* A4=(const float4*)(Wa + (size_t)g*64);
    const float4* B4=(const float4*)(Wb + (size_t)g*64);
    #pragma unroll
    for(int q=0;q<16;q++){
      float4 va=A4[q]; wa[4*q]=va.x; wa[4*q+1]=va.y; wa[4*q+2]=va.z; wa[4*q+3]=va.w;
      float4 vb=B4[q]; wb[4*q]=vb.x; wb[4*q+1]=vb.y; wb[4*q+2]=vb.z; wb[4*q+3]=vb.w;
    }
  }
  float biasa=ba1[g]+ba2[g], biasb=bb1[g]+bb2[g];
  __syncthreads();
  #pragma unroll
  for(int r=0;r<16;r++){
    const float4* x4=(const float4*)&xs[r*64];
    float a0=biasa,a1=0.f,b0=biasb,b1=0.f;
    #pragma unroll
    for(int kc=0;kc<16;kc++){
      float4 h4=x4[kc];
      a0=fmaf(wa[4*kc+0],h4.x,a0); b0=fmaf(wb[4*kc+0],h4.x,b0);
      a1=fmaf(wa[4*kc+1],h4.y,a1); b1=fmaf(wb[4*kc+1],h4.y,b1);
      a0=fmaf(wa[4*kc+2],h4.z,a0); b0=fmaf(wb[4*kc+2],h4.z,b0);
      a1=fmaf(wa[4*kc+3],h4.w,a1); b1=fmaf(wb[4*kc+3],h4.w,b1);
    }
    outa[(size_t)(m0+r)*256+g]=a0+a1;
    outb[(size_t)(m0+r)*256+g]=b0+b1;
  }
}

// ---------------- BiLSTM v5: exact R0 structure, drained-ops-made-old ----------------
// Evidence so far: R0 (__syncthreads, z_s[tid], dist-1 prefetch, store-at-bottom) = 112.7us.
// lgkm-only raw barriers (R2/V4) = ~129us: the "memory" asm makes the compiler emit a
// conservative vmcnt(0) before the xv use at matvec top -> exposed load latency. KEEP
// __syncthreads. Transposed z write = bank conflicts. KEEP z_s[tid] layout.
// v5 changes ONLY the age of the ops the barrier drains:
//  1) store h(s-1) at the TOP of step s (one wave, rotated w==((s-1)&3); h is redundant
//     in all waves) -> ~400-700cy elapse before the vmcnt(0) drain -> store-ack free.
//  2) prefetch distance 2 -> the xg load drained at step s's barrier was issued at s-1.
__global__ __launch_bounds__(256,1) void lstm_seq(const float* __restrict__ xg_f,
                                                  const float* __restrict__ xg_b,
                                                  const float* __restrict__ Whh_f,
                                                  const float* __restrict__ Whh_b,
                                                  float* __restrict__ hf,
                                                  float* __restrict__ hb){
  int tid=threadIdx.x, l=tid&63, w=tid>>6;
  int dir=blockIdx.x>>6, b=blockIdx.x&63;
  const float* xg = dir? xg_b : xg_f;
  const float* Whh= dir? Whh_b: Whh_f;
  float* out = dir? hb : hf;
  float wr[64];
  const float4* W4=(const float4*)(Whh+(size_t)(w*64+l)*64);
  #pragma unroll
  for(int q=0;q<16;q++){ float4 v=W4[q]; wr[4*q]=v.x; wr[4*q+1]=v.y; wr[4*q+2]=v.z; wr[4*q+3]=v.w; }
  __shared__ float z_s[2][256];
  float h=0.f, c=0.f;
  const int tstart = dir?(NKn-1):0, dt = dir?-1:1;
  const float* xgb  = xg  + (size_t)b*NKn*256 + w*64 + l;
  float*       outl = out + (size_t)b*NKn*64  + l;
  float xv  = xgb[(size_t)tstart*256];
  float xn1 = xgb[(size_t)(tstart+dt)*256];
  float h_prev=0.f; int t_prev=0;
  for(int s=0;s<NKn;s++){
    int t=tstart+s*dt;
    if (s>0 && w==((s-1)&3)) outl[(size_t)t_prev*64]=h_prev;   // store PREV h early (ages
                                                               // ~1 step before the drain)
    float xn2=0.f;
    if (s<NKn-2) xn2 = xgb[(size_t)(t+2*dt)*256];              // distance-2 prefetch
    float a0=xv,a1=0.f,a2=0.f,a3=0.f;
    #pragma unroll
    for(int q=0;q<16;q++){
      a0=fmaf(wr[4*q+0],rdl(h,4*q+0),a0);
      a1=fmaf(wr[4*q+1],rdl(h,4*q+1),a1);
      a2=fmaf(wr[4*q+2],rdl(h,4*q+2),a2);
      a3=fmaf(wr[4*q+3],rdl(h,4*q+3),a3);
    }
    z_s[s&1][tid]=(a0+a1)+(a2+a3);
    __syncthreads();                                 // double-buffered z -> only barrier
    float zi=z_s[s&1][l], zf=z_s[s&1][64+l], zg=z_s[s&1][128+l], zo=z_s[s&1][192+l];
    c = sigm_f(zf)*c + sigm_f(zi)*tanh_f(zg);        // redundant per wave, h stays in regs
    h = sigm_f(zo)*tanh_f(c);
    h_prev=h; t_prev=t;
    xv=xn1; xn1=xn2;
  }
  if (w==((NKn-1)&3)) outl[(size_t)t_prev*64]=h_prev;          // final step's h
}

// ---------------- zx GEMM (blocks 0..511) + combine/norms (blocks 512..1311) --------------
__global__ __launch_bounds__(256,2) void gemmz_combine(const float* __restrict__ tgt_enc,
                                                       const float* __restrict__ W,
                                                       const float* __restrict__ b1,
                                                       const float* __restrict__ b2,
                                                       float* __restrict__ zx,
                                                       const float* __restrict__ hf,
                                                       const float* __restrict__ hb,
                                                       const float* __restrict__ sup_enc,
                                                       float* __restrict__ semb,
                                                       float* __restrict__ sn){
  int tid=threadIdx.x, l=tid&63, w=tid>>6;
  int blk=blockIdx.x;
  if (blk < 512){
    int g=tid, m0=blk*16;
    __shared__ __attribute__((aligned(16))) float xs[16*64];
    #pragma unroll
    for(int q=0;q<4;q++){ int r=4*w+q; xs[r*64+l]=tgt_enc[(size_t)(m0+r)*64+l]; }
    float wr[64];
    const float4* W4=(const float4*)(W + (size_t)g*64);
    #pragma unroll
    for(int q=0;q<16;q++){ float4 v=W4[q]; wr[4*q]=v.x; wr[4*q+1]=v.y; wr[4*q+2]=v.z; wr[4*q+3]=v.w; }
    float bias=b1[g]+b2[g];
    __syncthreads();
    #pragma unroll
    for(int r=0;r<16;r++){
      const float4* x4=(const float4*)&xs[r*64];
      float a0=bias,a1=0.f,a2=0.f,a3=0.f;
      #pragma unroll
      for(int kc=0;kc<16;kc++){
        float4 h4=x4[kc];
        a0=fmaf(wr[4*kc+0],h4.x,a0);
        a1=fmaf(wr[4*kc+1],h4.y,a1);
        a2=fmaf(wr[4*kc+2],h4.z,a2);
        a3=fmaf(wr[4*kc+3],h4.w,a3);
      }
      zx[(size_t)(m0+r)*256+g]=(a0+a1)+(a2+a3);
    }
  } else {
    int m0=(blk-512)*16;
    #pragma unroll
    for(int q=0;q<4;q++){
      size_t m=(size_t)m0 + w*4 + q;
      float v = hf[m*64+l] + hb[m*64+l] + sup_enc[m*64+l];
      semb[m*64+l]=v;
      float s=v*v;
      #pragma unroll
      for (int o=32;o>0;o>>=1) s += __shfl_xor(s,o,64);
      if (l==0) sn[m]=sqrtf(s);
    }
  }
}

// ------- ALL 5 K-iterations + final cosine softmax in ONE kernel (row-local K loop) -------
// (256,1): ~200 live floats/thread must stay in arch VGPRs -> no spill (R8/R11 lesson:
// do NOT add a zx prologue; zx comes from global).
__global__ __launch_bounds__(256,1) void fused_K(const float* __restrict__ zx,
                                                 const float* __restrict__ Whh,
                                                 const float* __restrict__ x,
                                                 const float* __restrict__ semb,
                                                 const float* __restrict__ sn,
                                                 float* __restrict__ out){
  int tid=threadIdx.x, l=tid&63, w=tid>>6;
  int b=blockIdx.x>>3, t0=(blockIdx.x&7)*16;
  int m0=b*Tn+t0;
  int g=tid;                      // gate index AND support-row index j
  bool valid = g<NKn;
  const float* sbase = semb + (size_t)b*NKn*64;
  __shared__ __attribute__((aligned(16))) float hu_s[16*64];   // 4 KB
  __shared__ __attribute__((aligned(16))) float sbuf[16*256];  // z 16 KB / att[200*20]
  __shared__ __attribute__((aligned(16))) float hn_s[16*64];   // h_next 4 KB
  __shared__ float wredA[64], wredB[64];
  float wr[64], s4f[64];
  {
    const float4* W4=(const float4*)(Whh+(size_t)g*64);
    #pragma unroll
    for(int q=0;q<16;q++){ float4 v=W4[q]; wr[4*q]=v.x; wr[4*q+1]=v.y; wr[4*q+2]=v.z; wr[4*q+3]=v.w; }
  }
  if(valid){
    const float4* sp=(const float4*)(sbase+(size_t)g*64);
    #pragma unroll
    for(int q=0;q<16;q++){ float4 v=sp[q]; s4f[4*q]=v.x; s4f[4*q+1]=v.y; s4f[4*q+2]=v.z; s4f[4*q+3]=v.w; }
  } else {
    #pragma unroll
    for(int q=0;q<64;q++) s4f[q]=0.f;
  }
  float zxr[16];
  #pragma unroll
  for(int r=0;r<16;r++) zxr[r]=zx[(size_t)(m0+r)*256+g];
  float xr[4];
  #pragma unroll
  for(int q=0;q<4;q++) xr[q]=x[(size_t)(m0+q*4+w)*64+l];
  float snr = valid ? sn[(size_t)b*NKn+g] : 1.f;
  float cq[4]={0.f,0.f,0.f,0.f};
  float scr[16], ex[16], mx[16];
  for(int k=0;k<5;k++){
    if(k==0){
      #pragma unroll
      for(int r=0;r<16;r++){ sbuf[r*256+g]=zxr[r]; scr[r]=0.f; }
    } else {
      #pragma unroll
      for(int r=0;r<16;r++){
        float z0=zxr[r], z1=0.f, sc0=0.f, sc1=0.f;
        const float4* h4p=(const float4*)&hu_s[r*64];
        #pragma unroll
        for(int kc=0;kc<16;kc++){
          float4 h4=h4p[kc];
          z0 =fmaf(wr[4*kc+0] ,h4.x,z0 ); sc0=fmaf(s4f[4*kc+0],h4.x,sc0);
          z1 =fmaf(wr[4*kc+1] ,h4.y,z1 ); sc1=fmaf(s4f[4*kc+1],h4.y,sc1);
          z0 =fmaf(wr[4*kc+2] ,h4.z,z0 ); sc0=fmaf(s4f[4*kc+2],h4.z,sc0);
          z1 =fmaf(wr[4*kc+3] ,h4.w,z1 ); sc1=fmaf(s4f[4*kc+3],h4.w,sc1);
        }
        sbuf[r*256+g]=z0+z1;
        scr[r]=sc0+sc1;
      }
    }
    __syncthreads();                               // B1: z ready (hu_s reads done)
    #pragma unroll
    for(int q=0;q<4;q++){
      int r=q*4+w;
      float zi=sbuf[r*256+l], zf=sbuf[r*256+64+l], zg=sbuf[r*256+128+l], zo=sbuf[r*256+192+l];
      float c=sigm_f(zf)*cq[q]+sigm_f(zi)*tanh_f(zg);
      cq[q]=c;
      hn_s[r*64+l]=sigm_f(zo)*tanh_f(c)+xr[q];
    }
    if(k<4){
      #pragma unroll
      for(int t=0;t<16;t++){
        float m = valid ? scr[t] : -1e30f;
        #pragma unroll
        for(int o=32;o>0;o>>=1) m=fmaxf(m,__shfl_xor(m,o,64));
        mx[t]=m;
      }
      if(l==0){
        #pragma unroll
        for(int t=0;t<16;t++) wredA[t*4+w]=mx[t];
      }
      __syncthreads();                             // B2: z reads done; wredA ready
      #pragma unroll
      for(int t=0;t<16;t++){
        const float4 m4=*(const float4*)&wredA[t*4];
        float gm=fmaxf(fmaxf(m4.x,m4.y),fmaxf(m4.z,m4.w));
        float e=valid?__expf(scr[t]-gm):0.f;
        ex[t]=e;
        float s=e;
        #pragma unroll
        for(int o=32;o>0;o>>=1) s+=__shfl_xor(s,o,64);
        mx[t]=s;
      }
      if(l==0){
        #pragma unroll
        for(int t=0;t<16;t++) wredB[t*4+w]=mx[t];
      }
      __syncthreads();                             // B3: wredB ready
      #pragma unroll
      for(int t=0;t<16;t++){
        const float4 s4v=*(const float4*)&wredB[t*4];
        float tot=(s4v.x+s4v.y)+(s4v.z+s4v.w);
        ex[t]*=1.0f/tot;                           // att
      }
      if(valid){
        #pragma unroll
        for(int cg=0;cg<4;cg++)
          *(float4*)&sbuf[g*20+4*cg]=make_float4(ex[4*cg+0],ex[4*cg+1],ex[4*cg+2],ex[4*cg+3]);
      }
      __syncthreads();                             // B4: att + hn_s visible
      float r0=0.f,r1=0.f,r2=0.f,r3=0.f;
      #pragma unroll 8
      for(int j=0;j<NKn;j++){
        float4 a4=*(const float4*)&sbuf[j*20+w*4];
        float sv=sbase[(size_t)j*64+l];            // L2-resident, coalesced (VMEM pipe)
        r0=fmaf(a4.x,sv,r0);
        r1=fmaf(a4.y,sv,r1);
        r2=fmaf(a4.z,sv,r2);
        r3=fmaf(a4.w,sv,r3);
      }
      int rb=w*4;
      hu_s[(rb+0)*64+l]=r0 + hn_s[(rb+0)*64+l];
      hu_s[(rb+1)*64+l]=r1 + hn_s[(rb+1)*64+l];
      hu_s[(rb+2)*64+l]=r2 + hn_s[(rb+2)*64+l];
      hu_s[(rb+3)*64+l]=r3 + hn_s[(rb+3)*64+l];
      __syncthreads();                             // B5: hu ready for next iteration
    }
  }
  __syncthreads();                                 // hn_s complete
  float tnorm[16];
  #pragma unroll
  for(int t=0;t<16;t++){
    float v=hn_s[t*64+l];
    float s=v*v;
    #pragma unroll
    for(int o=32;o>0;o>>=1) s+=__shfl_xor(s,o,64);
    tnorm[t]=sqrtf(s);
  }
  #pragma unroll
  for(int t=0;t<16;t++){
    const float4* h4p=(const float4*)&hn_s[t*64];
    float a0=0.f,a1=0.f;
    #pragma unroll
    for(int kc=0;kc<16;kc++){
      float4 h4=h4p[kc];
      a0=fmaf(s4f[4*kc+0],h4.x,a0);
      a1=fmaf(s4f[4*kc+1],h4.y,a1);
      a0=fmaf(s4f[4*kc+2],h4.z,a0);
      a1=fmaf(s4f[4*kc+3],h4.w,a1);
    }
    scr[t]=(a0+a1) / fmaxf(tnorm[t]*snr,1e-8f);
  }
  #pragma unroll
  for(int t=0;t<16;t++){
    float m = valid ? scr[t] : -1e30f;
    #pragma unroll
    for(int o=32;o>0;o>>=1) m=fmaxf(m,__shfl_xor(m,o,64));
    mx[t]=m;
  }
  if(l==0){
    #pragma unroll
    for(int t=0;t<16;t++) wredA[t*4+w]=mx[t];
  }
  __syncthreads();
  #pragma unroll
  for(int t=0;t<16;t++){
    const float4 m4=*(const float4*)&wredA[t*4];
    float gm=fmaxf(fmaxf(m4.x,m4.y),fmaxf(m4.z,m4.w));
    float e=valid?__expf(scr[t]-gm):0.f;
    ex[t]=e;
    float s=e;
    #pragma unroll
    for(int o=32;o>0;o>>=1) s+=__shfl_xor(s,o,64);
    mx[t]=s;
  }
  if(l==0){
    #pragma unroll
    for(int t=0;t<16;t++) wredB[t*4+w]=mx[t];
  }
  __syncthreads();
  #pragma unroll
  for(int t=0;t<16;t++){
    const float4 s4v=*(const float4*)&wredB[t*4];
    float tot=(s4v.x+s4v.y)+(s4v.z+s4v.w);
    if(valid) out[((size_t)(m0+t))*NKn + g]=ex[t]*(1.0f/tot);
  }
}

extern "C" void kernel_launch(void* const* d_in, const int* in_sizes, int n_in,
                              void* d_out, int out_size, void* d_ws, size_t ws_size,
                              hipStream_t stream) {
  (void)in_sizes; (void)n_in; (void)out_size; (void)ws_size;
  const int*   sup_toks = (const int*)d_in[0];
  const int*   tgt_toks = (const int*)d_in[1];
  const float* emb      = (const float*)d_in[2];
  const float* f_Wih    = (const float*)d_in[3];
  const float* f_Whh    = (const float*)d_in[4];
  const float* f_bih    = (const float*)d_in[5];
  const float* f_bhh    = (const float*)d_in[6];
  const float* gf_Wih   = (const float*)d_in[7];
  const float* gf_Whh   = (const float*)d_in[8];
  const float* gf_bih   = (const float*)d_in[9];
  const float* gf_bhh   = (const float*)d_in[10];
  const float* gb_Wih   = (const float*)d_in[11];
  const float* gb_Whh   = (const float*)d_in[12];
  const float* gb_bih   = (const float*)d_in[13];
  const float* gb_bhh   = (const float*)d_in[14];

  float* ws = (float*)d_ws;
  float* sup_enc = ws;                         // 819200
  float* tgt_enc = sup_enc + 819200;           // 524288
  float* bufA    = tgt_enc + 524288;           // 3276800 : xg_f, later zx
  float* bufB    = bufA    + 3276800;          // 3276800 : xg_b
  float* semb    = bufB    + 3276800;          // 819200  : hf, then sup_emb
  float* hb      = semb    + 819200;           // 819200
  float* sn      = hb      + 819200;           // 12800

  float* xg_f = bufA;
  float* xg_b = bufB;

  embed_all<<<1312,256,0,stream>>>(sup_toks, tgt_toks, emb, sup_enc, tgt_enc);
  gemm_sup2<<<800,256,0,stream>>>(sup_enc, gf_Wih, gb_Wih,
                                  gf_bih, gf_bhh, gb_bih, gb_bhh, xg_f, xg_b);
  lstm_seq<<<128,256,0,stream>>>(xg_f, xg_b, gf_Whh, gb_Whh, semb /*hf*/, hb);

  float* zx = bufA;                    // xg_f dead after lstm

  gemmz_combine<<<1312,256,0,stream>>>(tgt_enc, f_Wih, f_bih, f_bhh, zx,
                                       semb, hb, sup_enc, semb, sn);

  fused_K<<<512,256,0,stream>>>(zx, f_Whh, tgt_enc, semb, sn, (float*)d_out);
}

// Round 7
// 352.475 us; speedup vs baseline: 1.0667x; 1.0205x over previous
//
#include <hip/hip_runtime.h>

#define Bn   64
#define Tn   128
#define NKn  200
#define En   64
#define Ln   40

__device__ __forceinline__ float sigm_f(float x){ return 1.0f/(1.0f+__expf(-x)); }
__device__ __forceinline__ float tanh_f(float x){ float e=__expf(2.0f*x); return 1.0f-2.0f/(e+1.0f); }
__device__ __forceinline__ float rdl(float v, int ln){
  return __uint_as_float(__builtin_amdgcn_readlane(__float_as_uint(v), (unsigned)ln));
}

// ---------------- support embedding gather-sum (sup only; tgt moved into gemm launch) ------
__global__ __launch_bounds__(256) void embed_sup(const int* __restrict__ sup,
                                                 const float* __restrict__ emb,
                                                 float* __restrict__ sup_enc){
  int tid = threadIdx.x;
  int gr  = blockIdx.x*16 + (tid>>4);
  int e4  = tid & 15;
  const int* tr = sup + (size_t)gr*Ln;
  float* out    = sup_enc + (size_t)gr*64;
  float4 acc = {0.f,0.f,0.f,0.f};
  #pragma unroll 4
  for (int t=0;t<Ln;t++){
    int tok = tr[t];
    float4 v = ((const float4*)emb)[(size_t)tok*16 + e4];
    acc.x+=v.x; acc.y+=v.y; acc.z+=v.z; acc.w+=v.w;
  }
  ((float4*)out)[e4] = acc;
}

// ------- support GEMMs (blocks 0..799) + INDEPENDENT tgt embedding (blocks 800..1311) ------
// tgt-embed depends only on tokens/emb; gemm depends only on sup_enc -> safe to co-schedule.
__global__ __launch_bounds__(256,1) void gemm_sup2_tgt(const float* __restrict__ x,
                                                   const float* __restrict__ Wa, const float* __restrict__ Wb,
                                                   const float* __restrict__ ba1,const float* __restrict__ ba2,
                                                   const float* __restrict__ bb1,const float* __restrict__ bb2,
                                                   float* __restrict__ outa, float* __restrict__ outb,
                                                   const int* __restrict__ tgt,
                                                   const float* __restrict__ emb,
                                                   float* __restrict__ tgt_enc){
  int tid=threadIdx.x, l=tid&63, w=tid>>6;
  if (blockIdx.x >= 800){                       // ---- tgt embedding gather-sum ----
    int r2 = (blockIdx.x-800)*16 + (tid>>4);
    int e4 = tid & 15;
    const int* tr = tgt + (size_t)r2*Ln;
    float4 acc = {0.f,0.f,0.f,0.f};
    #pragma unroll 4
    for (int t=0;t<Ln;t++){
      int tok = tr[t];
      float4 v = ((const float4*)emb)[(size_t)tok*16 + e4];
      acc.x+=v.x; acc.y+=v.y; acc.z+=v.z; acc.w+=v.w;
    }
    ((float4*)(tgt_enc + (size_t)r2*64))[e4] = acc;
    return;
  }
  int g=tid;
  int m0 = blockIdx.x*16;
  __shared__ __attribute__((aligned(16))) float xs[16*64];
  #pragma unroll
  for(int q=0;q<4;q++){ int r=4*w+q; xs[r*64+l]=x[(size_t)(m0+r)*64+l]; }
  float wa[64], wb[64];
  {
    const float4* A4=(const float4*)(Wa + (size_t)g*64);
    const float4* B4=(const float4*)(Wb + (size_t)g*64);
    #pragma unroll
    for(int q=0;q<16;q++){
      float4 va=A4[q]; wa[4*q]=va.x; wa[4*q+1]=va.y; wa[4*q+2]=va.z; wa[4*q+3]=va.w;
      float4 vb=B4[q]; wb[4*q]=vb.x; wb[4*q+1]=vb.y; wb[4*q+2]=vb.z; wb[4*q+3]=vb.w;
    }
  }
  float biasa=ba1[g]+ba2[g], biasb=bb1[g]+bb2[g];
  __syncthreads();
  #pragma unroll
  for(int r=0;r<16;r++){
    const float4* x4=(const float4*)&xs[r*64];
    float a0=biasa,a1=0.f,b0=biasb,b1=0.f;
    #pragma unroll
    for(int kc=0;kc<16;kc++){
      float4 h4=x4[kc];
      a0=fmaf(wa[4*kc+0],h4.x,a0); b0=fmaf(wb[4*kc+0],h4.x,b0);
      a1=fmaf(wa[4*kc+1],h4.y,a1); b1=fmaf(wb[4*kc+1],h4.y,b1);
      a0=fmaf(wa[4*kc+2],h4.z,a0); b0=fmaf(wb[4*kc+2],h4.z,b0);
      a1=fmaf(wa[4*kc+3],h4.w,a1); b1=fmaf(wb[4*kc+3],h4.w,b1);
    }
    outa[(size_t)(m0+r)*256+g]=a0+a1;
    outb[(size_t)(m0+r)*256+g]=b0+b1;
  }
}

// ------- BiLSTM (blocks 0..127, EXACT R0 structure) + INDEPENDENT zx GEMM (128..N) --------
// R0 is the measured best lstm (112.7us); six step-time variants all lost (R1..R6). The
// machine is 95% idle during lstm -> backfill with the zx GEMM (f_Wih@tgt_enc), which
// depends only on tgt_enc, NOT on the lstm. lstm blocks first so they start immediately;
// zx writes a DEDICATED buffer (cannot alias xg_f, which lstm reads concurrently).
__global__ __launch_bounds__(256,1) void lstm_zx(const float* __restrict__ xg_f,
                                                 const float* __restrict__ xg_b,
                                                 const float* __restrict__ Whh_f,
                                                 const float* __restrict__ Whh_b,
                                                 float* __restrict__ hf,
                                                 float* __restrict__ hb,
                                                 const float* __restrict__ tgt_enc,
                                                 const float* __restrict__ Wz,
                                                 const float* __restrict__ zb1,
                                                 const float* __restrict__ zb2,
                                                 float* __restrict__ zxp){
  int tid=threadIdx.x, l=tid&63, w=tid>>6;
  if (blockIdx.x < 128){
    // ---------------- exact R0 lstm ----------------
    int dir=blockIdx.x>>6, b=blockIdx.x&63;
    const float* xg = dir? xg_b : xg_f;
    const float* Whh= dir? Whh_b: Whh_f;
    float* out = dir? hb : hf;
    float wr[64];
    const float4* W4=(const float4*)(Whh+(size_t)(w*64+l)*64);
    #pragma unroll
    for(int q=0;q<16;q++){ float4 v=W4[q]; wr[4*q]=v.x; wr[4*q+1]=v.y; wr[4*q+2]=v.z; wr[4*q+3]=v.w; }
    __shared__ float z_s[2][256];
    float h=0.f, c=0.f;
    const int tstart = dir?(NKn-1):0, dt = dir?-1:1;
    const float* xgb = xg + (size_t)b*NKn*256 + w*64 + l;
    float xv = xgb[(size_t)tstart*256];
    for(int s=0;s<NKn;s++){
      int t=tstart+s*dt;
      float xnx=0.f;
      if (s<NKn-1) xnx = xgb[(size_t)(t+dt)*256];     // prefetch next step's xg
      float a0=xv,a1=0.f,a2=0.f,a3=0.f;
      #pragma unroll
      for(int q=0;q<16;q++){
        a0=fmaf(wr[4*q+0],rdl(h,4*q+0),a0);
        a1=fmaf(wr[4*q+1],rdl(h,4*q+1),a1);
        a2=fmaf(wr[4*q+2],rdl(h,4*q+2),a2);
        a3=fmaf(wr[4*q+3],rdl(h,4*q+3),a3);
      }
      z_s[s&1][tid]=(a0+a1)+(a2+a3);
      __syncthreads();                                 // double-buffered z -> only barrier
      float zi=z_s[s&1][l], zf=z_s[s&1][64+l], zg=z_s[s&1][128+l], zo=z_s[s&1][192+l];
      c = sigm_f(zf)*c + sigm_f(zi)*tanh_f(zg);        // redundant per wave, h stays in regs
      h = sigm_f(zo)*tanh_f(c);
      if(w==0) out[((size_t)b*NKn+t)*64+l]=h;
      xv=xnx;
    }
  } else {
    // ---------------- zx GEMM: zx = f_Wih @ tgt_enc + biases ----------------
    int g=tid, m0=(blockIdx.x-128)*16;
    __shared__ __attribute__((aligned(16))) float xs2[16*64];
    #pragma unroll
    for(int q=0;q<4;q++){ int r=4*w+q; xs2[r*64+l]=tgt_enc[(size_t)(m0+r)*64+l]; }
    float wr[64];
    const float4* W4=(const float4*)(Wz + (size_t)g*64);
    #pragma unroll
    for(int q=0;q<16;q++){ float4 v=W4[q]; wr[4*q]=v.x; wr[4*q+1]=v.y; wr[4*q+2]=v.z; wr[4*q+3]=v.w; }
    float bias=zb1[g]+zb2[g];
    __syncthreads();
    #pragma unroll
    for(int r=0;r<16;r++){
      const float4* x4=(const float4*)&xs2[r*64];
      float a0=bias,a1=0.f,a2=0.f,a3=0.f;
      #pragma unroll
      for(int kc=0;kc<16;kc++){
        float4 h4=x4[kc];
        a0=fmaf(wr[4*kc+0],h4.x,a0);
        a1=fmaf(wr[4*kc+1],h4.y,a1);
        a2=fmaf(wr[4*kc+2],h4.z,a2);
        a3=fmaf(wr[4*kc+3],h4.w,a3);
      }
      zxp[(size_t)(m0+r)*256+g]=(a0+a1)+(a2+a3);
    }
  }
}

// ---------------- combine/norms only (zx handled in lstm_zx when fused) ----------------
__global__ __launch_bounds__(256,2) void combine_norm(const float* __restrict__ hf,
                                                      const float* __restrict__ hb,
                                                      const float* __restrict__ sup_enc,
                                                      float* __restrict__ semb,
                                                      float* __restrict__ sn){
  int tid=threadIdx.x, l=tid&63, w=tid>>6;
  int m0=blockIdx.x*16;
  #pragma unroll
  for(int q=0;q<4;q++){
    size_t m=(size_t)m0 + w*4 + q;
    float v = hf[m*64+l] + hb[m*64+l] + sup_enc[m*64+l];
    semb[m*64+l]=v;
    float s=v*v;
    #pragma unroll
    for (int o=32;o>0;o>>=1) s += __shfl_xor(s,o,64);
    if (l==0) sn[m]=sqrtf(s);
  }
}

// ---------------- FALLBACK: zx GEMM + combine in one grid (original gemmz_combine) --------
__global__ __launch_bounds__(256,2) void gemmz_combine(const float* __restrict__ tgt_enc,
                                                       const float* __restrict__ W,
                                                       const float* __restrict__ b1,
                                                       const float* __restrict__ b2,
                                                       float* __restrict__ zx,
                                                       const float* __restrict__ hf,
                                                       const float* __restrict__ hb,
                                                       const float* __restrict__ sup_enc,
                                                       float* __restrict__ semb,
                                                       float* __restrict__ sn){
  int tid=threadIdx.x, l=tid&63, w=tid>>6;
  int blk=blockIdx.x;
  if (blk < 512){
    int g=tid, m0=blk*16;
    __shared__ __attribute__((aligned(16))) float xs[16*64];
    #pragma unroll
    for(int q=0;q<4;q++){ int r=4*w+q; xs[r*64+l]=tgt_enc[(size_t)(m0+r)*64+l]; }
    float wr[64];
    const float4* W4=(const float4*)(W + (size_t)g*64);
    #pragma unroll
    for(int q=0;q<16;q++){ float4 v=W4[q]; wr[4*q]=v.x; wr[4*q+1]=v.y; wr[4*q+2]=v.z; wr[4*q+3]=v.w; }
    float bias=b1[g]+b2[g];
    __syncthreads();
    #pragma unroll
    for(int r=0;r<16;r++){
      const float4* x4=(const float4*)&xs[r*64];
      float a0=bias,a1=0.f,a2=0.f,a3=0.f;
      #pragma unroll
      for(int kc=0;kc<16;kc++){
        float4 h4=x4[kc];
        a0=fmaf(wr[4*kc+0],h4.x,a0);
        a1=fmaf(wr[4*kc+1],h4.y,a1);
        a2=fmaf(wr[4*kc+2],h4.z,a2);
        a3=fmaf(wr[4*kc+3],h4.w,a3);
      }
      zx[(size_t)(m0+r)*256+g]=(a0+a1)+(a2+a3);
    }
  } else {
    int m0=(blk-512)*16;
    #pragma unroll
    for(int q=0;q<4;q++){
      size_t m=(size_t)m0 + w*4 + q;
      float v = hf[m*64+l] + hb[m*64+l] + sup_enc[m*64+l];
      semb[m*64+l]=v;
      float s=v*v;
      #pragma unroll
      for (int o=32;o>0;o>>=1) s += __shfl_xor(s,o,64);
      if (l==0) sn[m]=sqrtf(s);
    }
  }
}

// ------- ALL 5 K-iterations + final cosine softmax in ONE kernel (row-local K loop) -------
// (256,1): ~200 live floats/thread must stay in arch VGPRs -> no spill (R8/R11 lesson:
// do NOT add a zx prologue; zx comes from global).
__global__ __launch_bounds__(256,1) void fused_K(const float* __restrict__ zx,
                                                 const float* __restrict__ Whh,
                                                 const float* __restrict__ x,
                                                 const float* __restrict__ semb,
                                                 const float* __restrict__ sn,
                                                 float* __restrict__ out){
  int tid=threadIdx.x, l=tid&63, w=tid>>6;
  int b=blockIdx.x>>3, t0=(blockIdx.x&7)*16;
  int m0=b*Tn+t0;
  int g=tid;                      // gate index AND support-row index j
  bool valid = g<NKn;
  const float* sbase = semb + (size_t)b*NKn*64;
  __shared__ __attribute__((aligned(16))) float hu_s[16*64];   // 4 KB
  __shared__ __attribute__((aligned(16))) float sbuf[16*256];  // z 16 KB / att[200*20]
  __shared__ __attribute__((aligned(16))) float hn_s[16*64];   // h_next 4 KB
  __shared__ float wredA[64], wredB[64];
  float wr[64], s4f[64];
  {
    const float4* W4=(const float4*)(Whh+(size_t)g*64);
    #pragma unroll
    for(int q=0;q<16;q++){ float4 v=W4[q]; wr[4*q]=v.x; wr[4*q+1]=v.y; wr[4*q+2]=v.z; wr[4*q+3]=v.w; }
  }
  if(valid){
    const float4* sp=(const float4*)(sbase+(size_t)g*64);
    #pragma unroll
    for(int q=0;q<16;q++){ float4 v=sp[q]; s4f[4*q]=v.x; s4f[4*q+1]=v.y; s4f[4*q+2]=v.z; s4f[4*q+3]=v.w; }
  } else {
    #pragma unroll
    for(int q=0;q<64;q++) s4f[q]=0.f;
  }
  float zxr[16];
  #pragma unroll
  for(int r=0;r<16;r++) zxr[r]=zx[(size_t)(m0+r)*256+g];
  float xr[4];
  #pragma unroll
  for(int q=0;q<4;q++) xr[q]=x[(size_t)(m0+q*4+w)*64+l];
  float snr = valid ? sn[(size_t)b*NKn+g] : 1.f;
  float cq[4]={0.f,0.f,0.f,0.f};
  float scr[16], ex[16], mx[16];
  for(int k=0;k<5;k++){
    if(k==0){
      #pragma unroll
      for(int r=0;r<16;r++){ sbuf[r*256+g]=zxr[r]; scr[r]=0.f; }
    } else {
      #pragma unroll
      for(int r=0;r<16;r++){
        float z0=zxr[r], z1=0.f, sc0=0.f, sc1=0.f;
        const float4* h4p=(const float4*)&hu_s[r*64];
        #pragma unroll
        for(int kc=0;kc<16;kc++){
          float4 h4=h4p[kc];
          z0 =fmaf(wr[4*kc+0] ,h4.x,z0 ); sc0=fmaf(s4f[4*kc+0],h4.x,sc0);
          z1 =fmaf(wr[4*kc+1] ,h4.y,z1 ); sc1=fmaf(s4f[4*kc+1],h4.y,sc1);
          z0 =fmaf(wr[4*kc+2] ,h4.z,z0 ); sc0=fmaf(s4f[4*kc+2],h4.z,sc0);
          z1 =fmaf(wr[4*kc+3] ,h4.w,z1 ); sc1=fmaf(s4f[4*kc+3],h4.w,sc1);
        }
        sbuf[r*256+g]=z0+z1;
        scr[r]=sc0+sc1;
      }
    }
    __syncthreads();                               // B1: z ready (hu_s reads done)
    #pragma unroll
    for(int q=0;q<4;q++){
      int r=q*4+w;
      float zi=sbuf[r*256+l], zf=sbuf[r*256+64+l], zg=sbuf[r*256+128+l], zo=sbuf[r*256+192+l];
      float c=sigm_f(zf)*cq[q]+sigm_f(zi)*tanh_f(zg);
      cq[q]=c;
      hn_s[r*64+l]=sigm_f(zo)*tanh_f(c)+xr[q];
    }
    if(k<4){
      #pragma unroll
      for(int t=0;t<16;t++){
        float m = valid ? scr[t] : -1e30f;
        #pragma unroll
        for(int o=32;o>0;o>>=1) m=fmaxf(m,__shfl_xor(m,o,64));
        mx[t]=m;
      }
      if(l==0){
        #pragma unroll
        for(int t=0;t<16;t++) wredA[t*4+w]=mx[t];
      }
      __syncthreads();                             // B2: z reads done; wredA ready
      #pragma unroll
      for(int t=0;t<16;t++){
        const float4 m4=*(const float4*)&wredA[t*4];
        float gm=fmaxf(fmaxf(m4.x,m4.y),fmaxf(m4.z,m4.w));
        float e=valid?__expf(scr[t]-gm):0.f;
        ex[t]=e;
        float s=e;
        #pragma unroll
        for(int o=32;o>0;o>>=1) s+=__shfl_xor(s,o,64);
        mx[t]=s;
      }
      if(l==0){
        #pragma unroll
        for(int t=0;t<16;t++) wredB[t*4+w]=mx[t];
      }
      __syncthreads();                             // B3: wredB ready
      #pragma unroll
      for(int t=0;t<16;t++){
        const float4 s4v=*(const float4*)&wredB[t*4];
        float tot=(s4v.x+s4v.y)+(s4v.z+s4v.w);
        ex[t]*=1.0f/tot;                           // att
      }
      if(valid){
        #pragma unroll
        for(int cg=0;cg<4;cg++)
          *(float4*)&sbuf[g*20+4*cg]=make_float4(ex[4*cg+0],ex[4*cg+1],ex[4*cg+2],ex[4*cg+3]);
      }
      __syncthreads();                             // B4: att + hn_s visible
      float r0=0.f,r1=0.f,r2=0.f,r3=0.f;
      #pragma unroll 8
      for(int j=0;j<NKn;j++){
        float4 a4=*(const float4*)&sbuf[j*20+w*4];
        float sv=sbase[(size_t)j*64+l];            // L2-resident, coalesced (VMEM pipe)
        r0=fmaf(a4.x,sv,r0);
        r1=fmaf(a4.y,sv,r1);
        r2=fmaf(a4.z,sv,r2);
        r3=fmaf(a4.w,sv,r3);
      }
      int rb=w*4;
      hu_s[(rb+0)*64+l]=r0 + hn_s[(rb+0)*64+l];
      hu_s[(rb+1)*64+l]=r1 + hn_s[(rb+1)*64+l];
      hu_s[(rb+2)*64+l]=r2 + hn_s[(rb+2)*64+l];
      hu_s[(rb+3)*64+l]=r3 + hn_s[(rb+3)*64+l];
      __syncthreads();                             // B5: hu ready for next iteration
    }
  }
  __syncthreads();                                 // hn_s complete
  float tnorm[16];
  #pragma unroll
  for(int t=0;t<16;t++){
    float v=hn_s[t*64+l];
    float s=v*v;
    #pragma unroll
    for(int o=32;o>0;o>>=1) s+=__shfl_xor(s,o,64);
    tnorm[t]=sqrtf(s);
  }
  #pragma unroll
  for(int t=0;t<16;t++){
    const float4* h4p=(const float4*)&hn_s[t*64];
    float a0=0.f,a1=0.f;
    #pragma unroll
    for(int kc=0;kc<16;kc++){
      float4 h4=h4p[kc];
      a0=fmaf(s4f[4*kc+0],h4.x,a0);
      a1=fmaf(s4f[4*kc+1],h4.y,a1);
      a0=fmaf(s4f[4*kc+2],h4.z,a0);
      a1=fmaf(s4f[4*kc+3],h4.w,a1);
    }
    scr[t]=(a0+a1) / fmaxf(tnorm[t]*snr,1e-8f);
  }
  #pragma unroll
  for(int t=0;t<16;t++){
    float m = valid ? scr[t] : -1e30f;
    #pragma unroll
    for(int o=32;o>0;o>>=1) m=fmaxf(m,__shfl_xor(m,o,64));
    mx[t]=m;
  }
  if(l==0){
    #pragma unroll
    for(int t=0;t<16;t++) wredA[t*4+w]=mx[t];
  }
  __syncthreads();
  #pragma unroll
  for(int t=0;t<16;t++){
    const float4 m4=*(const float4*)&wredA[t*4];
    float gm=fmaxf(fmaxf(m4.x,m4.y),fmaxf(m4.z,m4.w));
    float e=valid?__expf(scr[t]-gm):0.f;
    ex[t]=e;
    float s=e;
    #pragma unroll
    for(int o=32;o>0;o>>=1) s+=__shfl_xor(s,o,64);
    mx[t]=s;
  }
  if(l==0){
    #pragma unroll
    for(int t=0;t<16;t++) wredB[t*4+w]=mx[t];
  }
  __syncthreads();
  #pragma unroll
  for(int t=0;t<16;t++){
    const float4 s4v=*(const float4*)&wredB[t*4];
    float tot=(s4v.x+s4v.y)+(s4v.z+s4v.w);
    if(valid) out[((size_t)(m0+t))*NKn + g]=ex[t]*(1.0f/tot);
  }
}

extern "C" void kernel_launch(void* const* d_in, const int* in_sizes, int n_in,
                              void* d_out, int out_size, void* d_ws, size_t ws_size,
                              hipStream_t stream) {
  (void)in_sizes; (void)n_in; (void)out_size;
  const int*   sup_toks = (const int*)d_in[0];
  const int*   tgt_toks = (const int*)d_in[1];
  const float* emb      = (const float*)d_in[2];
  const float* f_Wih    = (const float*)d_in[3];
  const float* f_Whh    = (const float*)d_in[4];
  const float* f_bih    = (const float*)d_in[5];
  const float* f_bhh    = (const float*)d_in[6];
  const float* gf_Wih   = (const float*)d_in[7];
  const float* gf_Whh   = (const float*)d_in[8];
  const float* gf_bih   = (const float*)d_in[9];
  const float* gf_bhh   = (const float*)d_in[10];
  const float* gb_Wih   = (const float*)d_in[11];
  const float* gb_Whh   = (const float*)d_in[12];
  const float* gb_bih   = (const float*)d_in[13];
  const float* gb_bhh   = (const float*)d_in[14];

  float* ws = (float*)d_ws;
  float* sup_enc = ws;                         // 819200
  float* tgt_enc = sup_enc + 819200;           // 524288
  float* bufA    = tgt_enc + 524288;           // 3276800 : xg_f (fallback: zx after lstm)
  float* bufB    = bufA    + 3276800;          // 3276800 : xg_b
  float* semb    = bufB    + 3276800;          // 819200  : hf, then sup_emb
  float* hb      = semb    + 819200;           // 819200
  float* sn      = hb      + 819200;           // 12800
  float* zxded   = sn      + 12800;            // 2097152 : dedicated zx (fused path only)

  // fused path needs (9548288 + 2097152) floats of workspace
  bool fused = ws_size >= (size_t)(9548288 + 2097152) * sizeof(float);
  float* zx = fused ? zxded : bufA;

  float* xg_f = bufA;
  float* xg_b = bufB;

  embed_sup<<<800,256,0,stream>>>(sup_toks, emb, sup_enc);
  gemm_sup2_tgt<<<1312,256,0,stream>>>(sup_enc, gf_Wih, gb_Wih,
                                       gf_bih, gf_bhh, gb_bih, gb_bhh, xg_f, xg_b,
                                       tgt_toks, emb, tgt_enc);
  if (fused){
    // lstm (blocks 0..127) + zx GEMM (blocks 128..639) co-scheduled on the idle CUs
    lstm_zx<<<640,256,0,stream>>>(xg_f, xg_b, gf_Whh, gb_Whh, semb /*hf*/, hb,
                                  tgt_enc, f_Wih, f_bih, f_bhh, zx);
    combine_norm<<<800,256,0,stream>>>(semb /*hf*/, hb, sup_enc, semb, sn);
  } else {
    lstm_zx<<<128,256,0,stream>>>(xg_f, xg_b, gf_Whh, gb_Whh, semb /*hf*/, hb,
                                  tgt_enc, f_Wih, f_bih, f_bhh, zx);
    gemmz_combine<<<1312,256,0,stream>>>(tgt_enc, f_Wih, f_bih, f_bhh, zx,
                                         semb, hb, sup_enc, semb, sn);
  }
  fused_K<<<512,256,0,stream>>>(zx, f_Whh, tgt_enc, semb, sn, (float*)d_out);
}

// Round 8
// 345.643 us; speedup vs baseline: 1.0877x; 1.0198x over previous
//
#include <hip/hip_runtime.h>

#define Bn   64
#define Tn   128
#define NKn  200
#define En   64
#define Ln   40

__device__ __forceinline__ float sigm_f(float x){ return 1.0f/(1.0f+__expf(-x)); }
__device__ __forceinline__ float tanh_f(float x){ float e=__expf(2.0f*x); return 1.0f-2.0f/(e+1.0f); }
__device__ __forceinline__ float rdl(float v, int ln){
  return __uint_as_float(__builtin_amdgcn_readlane(__float_as_uint(v), (unsigned)ln));
}

// ---- support embed (fused into GEMM below) + support GEMMs + tgt embedding, ONE kernel ----
// Block tilings are 1:1: gemm block m0=blk*16 consumes exactly the 16 sup_enc rows that
// embed block blk produced -> compute the gather-sum straight into the xs LDS tile (and
// mirror to global sup_enc for combine_norm). Blocks 800..1311 do the independent tgt embed.
__global__ __launch_bounds__(256,1) void gemm_sup2_tgt(const int* __restrict__ sup,
                                                   const float* __restrict__ emb,
                                                   float* __restrict__ sup_enc,
                                                   const float* __restrict__ Wa, const float* __restrict__ Wb,
                                                   const float* __restrict__ ba1,const float* __restrict__ ba2,
                                                   const float* __restrict__ bb1,const float* __restrict__ bb2,
                                                   float* __restrict__ outa, float* __restrict__ outb,
                                                   const int* __restrict__ tgt,
                                                   float* __restrict__ tgt_enc){
  int tid=threadIdx.x, l=tid&63, w=tid>>6;
  if (blockIdx.x >= 800){                       // ---- tgt embedding gather-sum ----
    int r2 = (blockIdx.x-800)*16 + (tid>>4);
    int e4 = tid & 15;
    const int* tr = tgt + (size_t)r2*Ln;
    float4 acc = {0.f,0.f,0.f,0.f};
    #pragma unroll 4
    for (int t=0;t<Ln;t++){
      int tok = tr[t];
      float4 v = ((const float4*)emb)[(size_t)tok*16 + e4];
      acc.x+=v.x; acc.y+=v.y; acc.z+=v.z; acc.w+=v.w;
    }
    ((float4*)(tgt_enc + (size_t)r2*64))[e4] = acc;
    return;
  }
  int g=tid;
  int m0 = blockIdx.x*16;
  __shared__ __attribute__((aligned(16))) float xs[16*64];
  {                                             // ---- fused sup embed -> LDS + global ----
    int r = tid>>4, e4 = tid&15;
    const int* tr = sup + (size_t)(m0+r)*Ln;
    float4 acc = {0.f,0.f,0.f,0.f};
    #pragma unroll 4
    for (int t=0;t<Ln;t++){
      int tok = tr[t];
      float4 v = ((const float4*)emb)[(size_t)tok*16 + e4];
      acc.x+=v.x; acc.y+=v.y; acc.z+=v.z; acc.w+=v.w;
    }
    ((float4*)&xs[r*64])[e4] = acc;
    ((float4*)(sup_enc + (size_t)(m0+r)*64))[e4] = acc;   // combine_norm reads this later
  }
  float wa[64], wb[64];
  {
    const float4* A4=(const float4*)(Wa + (size_t)g*64);
    const float4* B4=(const float4*)(Wb + (size_t)g*64);
    #pragma unroll
    for(int q=0;q<16;q++){
      float4 va=A4[q]; wa[4*q]=va.x; wa[4*q+1]=va.y; wa[4*q+2]=va.z; wa[4*q+3]=va.w;
      float4 vb=B4[q]; wb[4*q]=vb.x; wb[4*q+1]=vb.y; wb[4*q+2]=vb.z; wb[4*q+3]=vb.w;
    }
  }
  float biasa=ba1[g]+ba2[g], biasb=bb1[g]+bb2[g];
  __syncthreads();
  #pragma unroll
  for(int r=0;r<16;r++){
    const float4* x4=(const float4*)&xs[r*64];
    float a0=biasa,a1=0.f,b0=biasb,b1=0.f;
    #pragma unroll
    for(int kc=0;kc<16;kc++){
      float4 h4=x4[kc];
      a0=fmaf(wa[4*kc+0],h4.x,a0); b0=fmaf(wb[4*kc+0],h4.x,b0);
      a1=fmaf(wa[4*kc+1],h4.y,a1); b1=fmaf(wb[4*kc+1],h4.y,b1);
      a0=fmaf(wa[4*kc+2],h4.z,a0); b0=fmaf(wb[4*kc+2],h4.z,b0);
      a1=fmaf(wa[4*kc+3],h4.w,a1); b1=fmaf(wb[4*kc+3],h4.w,b1);
    }
    outa[(size_t)(m0+r)*256+g]=a0+a1;
    outb[(size_t)(m0+r)*256+g]=b0+b1;
  }
}

// ------- BiLSTM (blocks 0..127, EXACT R0 structure, setprio(1)) + zx GEMM (128..N) --------
// R0 is the measured best lstm (112.7us). R7 showed co-resident zx waves cost +14.5us of
// SIMD issue competition. s_setprio(1) on the lstm waves (T5: independent waves, different
// phases -> priority pays; zx has ~10x slack so starving it is free).
__global__ __launch_bounds__(256,1) void lstm_zx(const float* __restrict__ xg_f,
                                                 const float* __restrict__ xg_b,
                                                 const float* __restrict__ Whh_f,
                                                 const float* __restrict__ Whh_b,
                                                 float* __restrict__ hf,
                                                 float* __restrict__ hb,
                                                 const float* __restrict__ tgt_enc,
                                                 const float* __restrict__ Wz,
                                                 const float* __restrict__ zb1,
                                                 const float* __restrict__ zb2,
                                                 float* __restrict__ zxp){
  int tid=threadIdx.x, l=tid&63, w=tid>>6;
  if (blockIdx.x < 128){
    __builtin_amdgcn_s_setprio(1);              // lstm waves win SIMD arbitration vs zx
    // ---------------- exact R0 lstm ----------------
    int dir=blockIdx.x>>6, b=blockIdx.x&63;
    const float* xg = dir? xg_b : xg_f;
    const float* Whh= dir? Whh_b: Whh_f;
    float* out = dir? hb : hf;
    float wr[64];
    const float4* W4=(const float4*)(Whh+(size_t)(w*64+l)*64);
    #pragma unroll
    for(int q=0;q<16;q++){ float4 v=W4[q]; wr[4*q]=v.x; wr[4*q+1]=v.y; wr[4*q+2]=v.z; wr[4*q+3]=v.w; }
    __shared__ float z_s[2][256];
    float h=0.f, c=0.f;
    const int tstart = dir?(NKn-1):0, dt = dir?-1:1;
    const float* xgb = xg + (size_t)b*NKn*256 + w*64 + l;
    float xv = xgb[(size_t)tstart*256];
    for(int s=0;s<NKn;s++){
      int t=tstart+s*dt;
      float xnx=0.f;
      if (s<NKn-1) xnx = xgb[(size_t)(t+dt)*256];     // prefetch next step's xg
      float a0=xv,a1=0.f,a2=0.f,a3=0.f;
      #pragma unroll
      for(int q=0;q<16;q++){
        a0=fmaf(wr[4*q+0],rdl(h,4*q+0),a0);
        a1=fmaf(wr[4*q+1],rdl(h,4*q+1),a1);
        a2=fmaf(wr[4*q+2],rdl(h,4*q+2),a2);
        a3=fmaf(wr[4*q+3],rdl(h,4*q+3),a3);
      }
      z_s[s&1][tid]=(a0+a1)+(a2+a3);
      __syncthreads();                                 // double-buffered z -> only barrier
      float zi=z_s[s&1][l], zf=z_s[s&1][64+l], zg=z_s[s&1][128+l], zo=z_s[s&1][192+l];
      c = sigm_f(zf)*c + sigm_f(zi)*tanh_f(zg);        // redundant per wave, h stays in regs
      h = sigm_f(zo)*tanh_f(c);
      if(w==0) out[((size_t)b*NKn+t)*64+l]=h;
      xv=xnx;
    }
  } else {
    // ---------------- zx GEMM: zx = f_Wih @ tgt_enc + biases ----------------
    int g=tid, m0=(blockIdx.x-128)*16;
    __shared__ __attribute__((aligned(16))) float xs2[16*64];
    #pragma unroll
    for(int q=0;q<4;q++){ int r=4*w+q; xs2[r*64+l]=tgt_enc[(size_t)(m0+r)*64+l]; }
    float wr[64];
    const float4* W4=(const float4*)(Wz + (size_t)g*64);
    #pragma unroll
    for(int q=0;q<16;q++){ float4 v=W4[q]; wr[4*q]=v.x; wr[4*q+1]=v.y; wr[4*q+2]=v.z; wr[4*q+3]=v.w; }
    float bias=zb1[g]+zb2[g];
    __syncthreads();
    #pragma unroll
    for(int r=0;r<16;r++){
      const float4* x4=(const float4*)&xs2[r*64];
      float a0=bias,a1=0.f,a2=0.f,a3=0.f;
      #pragma unroll
      for(int kc=0;kc<16;kc++){
        float4 h4=x4[kc];
        a0=fmaf(wr[4*kc+0],h4.x,a0);
        a1=fmaf(wr[4*kc+1],h4.y,a1);
        a2=fmaf(wr[4*kc+2],h4.z,a2);
        a3=fmaf(wr[4*kc+3],h4.w,a3);
      }
      zxp[(size_t)(m0+r)*256+g]=(a0+a1)+(a2+a3);
    }
  }
}

// ---------------- combine/norms only (zx handled in lstm_zx when fused) ----------------
__global__ __launch_bounds__(256,2) void combine_norm(const float* __restrict__ hf,
                                                      const float* __restrict__ hb,
                                                      const float* __restrict__ sup_enc,
                                                      float* __restrict__ semb,
                                                      float* __restrict__ sn){
  int tid=threadIdx.x, l=tid&63, w=tid>>6;
  int m0=blockIdx.x*16;
  #pragma unroll
  for(int q=0;q<4;q++){
    size_t m=(size_t)m0 + w*4 + q;
    float v = hf[m*64+l] + hb[m*64+l] + sup_enc[m*64+l];
    semb[m*64+l]=v;
    float s=v*v;
    #pragma unroll
    for (int o=32;o>0;o>>=1) s += __shfl_xor(s,o,64);
    if (l==0) sn[m]=sqrtf(s);
  }
}

// ---------------- FALLBACK: zx GEMM + combine in one grid (original gemmz_combine) --------
__global__ __launch_bounds__(256,2) void gemmz_combine(const float* __restrict__ tgt_enc,
                                                       const float* __restrict__ W,
                                                       const float* __restrict__ b1,
                                                       const float* __restrict__ b2,
                                                       float* __restrict__ zx,
                                                       const float* __restrict__ hf,
                                                       const float* __restrict__ hb,
                                                       const float* __restrict__ sup_enc,
                                                       float* __restrict__ semb,
                                                       float* __restrict__ sn){
  int tid=threadIdx.x, l=tid&63, w=tid>>6;
  int blk=blockIdx.x;
  if (blk < 512){
    int g=tid, m0=blk*16;
    __shared__ __attribute__((aligned(16))) float xs[16*64];
    #pragma unroll
    for(int q=0;q<4;q++){ int r=4*w+q; xs[r*64+l]=tgt_enc[(size_t)(m0+r)*64+l]; }
    float wr[64];
    const float4* W4=(const float4*)(W + (size_t)g*64);
    #pragma unroll
    for(int q=0;q<16;q++){ float4 v=W4[q]; wr[4*q]=v.x; wr[4*q+1]=v.y; wr[4*q+2]=v.z; wr[4*q+3]=v.w; }
    float bias=b1[g]+b2[g];
    __syncthreads();
    #pragma unroll
    for(int r=0;r<16;r++){
      const float4* x4=(const float4*)&xs[r*64];
      float a0=bias,a1=0.f,a2=0.f,a3=0.f;
      #pragma unroll
      for(int kc=0;kc<16;kc++){
        float4 h4=x4[kc];
        a0=fmaf(wr[4*kc+0],h4.x,a0);
        a1=fmaf(wr[4*kc+1],h4.y,a1);
        a2=fmaf(wr[4*kc+2],h4.z,a2);
        a3=fmaf(wr[4*kc+3],h4.w,a3);
      }
      zx[(size_t)(m0+r)*256+g]=(a0+a1)+(a2+a3);
    }
  } else {
    int m0=(blk-512)*16;
    #pragma unroll
    for(int q=0;q<4;q++){
      size_t m=(size_t)m0 + w*4 + q;
      float v = hf[m*64+l] + hb[m*64+l] + sup_enc[m*64+l];
      semb[m*64+l]=v;
      float s=v*v;
      #pragma unroll
      for (int o=32;o>0;o>>=1) s += __shfl_xor(s,o,64);
      if (l==0) sn[m]=sqrtf(s);
    }
  }
}

// ------- ALL 5 K-iterations + final cosine softmax in ONE kernel (row-local K loop) -------
// (256,1): ~200 live floats/thread must stay in arch VGPRs -> no spill (R8/R11 lesson:
// do NOT add a zx prologue; zx comes from global).
__global__ __launch_bounds__(256,1) void fused_K(const float* __restrict__ zx,
                                                 const float* __restrict__ Whh,
                                                 const float* __restrict__ x,
                                                 const float* __restrict__ semb,
                                                 const float* __restrict__ sn,
                                                 float* __restrict__ out){
  int tid=threadIdx.x, l=tid&63, w=tid>>6;
  int b=blockIdx.x>>3, t0=(blockIdx.x&7)*16;
  int m0=b*Tn+t0;
  int g=tid;                      // gate index AND support-row index j
  bool valid = g<NKn;
  const float* sbase = semb + (size_t)b*NKn*64;
  __shared__ __attribute__((aligned(16))) float hu_s[16*64];   // 4 KB
  __shared__ __attribute__((aligned(16))) float sbuf[16*256];  // z 16 KB / att[200*20]
  __shared__ __attribute__((aligned(16))) float hn_s[16*64];   // h_next 4 KB
  __shared__ float wredA[64], wredB[64];
  float wr[64], s4f[64];
  {
    const float4* W4=(const float4*)(Whh+(size_t)g*64);
    #pragma unroll
    for(int q=0;q<16;q++){ float4 v=W4[q]; wr[4*q]=v.x; wr[4*q+1]=v.y; wr[4*q+2]=v.z; wr[4*q+3]=v.w; }
  }
  if(valid){
    const float4* sp=(const float4*)(sbase+(size_t)g*64);
    #pragma unroll
    for(int q=0;q<16;q++){ float4 v=sp[q]; s4f[4*q]=v.x; s4f[4*q+1]=v.y; s4f[4*q+2]=v.z; s4f[4*q+3]=v.w; }
  } else {
    #pragma unroll
    for(int q=0;q<64;q++) s4f[q]=0.f;
  }
  float zxr[16];
  #pragma unroll
  for(int r=0;r<16;r++) zxr[r]=zx[(size_t)(m0+r)*256+g];
  float xr[4];
  #pragma unroll
  for(int q=0;q<4;q++) xr[q]=x[(size_t)(m0+q*4+w)*64+l];
  float snr = valid ? sn[(size_t)b*NKn+g] : 1.f;
  float cq[4]={0.f,0.f,0.f,0.f};
  float scr[16], ex[16], mx[16];
  for(int k=0;k<5;k++){
    if(k==0){
      #pragma unroll
      for(int r=0;r<16;r++){ sbuf[r*256+g]=zxr[r]; scr[r]=0.f; }
    } else {
      #pragma unroll
      for(int r=0;r<16;r++){
        float z0=zxr[r], z1=0.f, sc0=0.f, sc1=0.f;
        const float4* h4p=(const float4*)&hu_s[r*64];
        #pragma unroll
        for(int kc=0;kc<16;kc++){
          float4 h4=h4p[kc];
          z0 =fmaf(wr[4*kc+0] ,h4.x,z0 ); sc0=fmaf(s4f[4*kc+0],h4.x,sc0);
          z1 =fmaf(wr[4*kc+1] ,h4.y,z1 ); sc1=fmaf(s4f[4*kc+1],h4.y,sc1);
          z0 =fmaf(wr[4*kc+2] ,h4.z,z0 ); sc0=fmaf(s4f[4*kc+2],h4.z,sc0);
          z1 =fmaf(wr[4*kc+3] ,h4.w,z1 ); sc1=fmaf(s4f[4*kc+3],h4.w,sc1);
        }
        sbuf[r*256+g]=z0+z1;
        scr[r]=sc0+sc1;
      }
    }
    __syncthreads();                               // B1: z ready (hu_s reads done)
    #pragma unroll
    for(int q=0;q<4;q++){
      int r=q*4+w;
      float zi=sbuf[r*256+l], zf=sbuf[r*256+64+l], zg=sbuf[r*256+128+l], zo=sbuf[r*256+192+l];
      float c=sigm_f(zf)*cq[q]+sigm_f(zi)*tanh_f(zg);
      cq[q]=c;
      hn_s[r*64+l]=sigm_f(zo)*tanh_f(c)+xr[q];
    }
    if(k<4){
      #pragma unroll
      for(int t=0;t<16;t++){
        float m = valid ? scr[t] : -1e30f;
        #pragma unroll
        for(int o=32;o>0;o>>=1) m=fmaxf(m,__shfl_xor(m,o,64));
        mx[t]=m;
      }
      if(l==0){
        #pragma unroll
        for(int t=0;t<16;t++) wredA[t*4+w]=mx[t];
      }
      __syncthreads();                             // B2: z reads done; wredA ready
      #pragma unroll
      for(int t=0;t<16;t++){
        const float4 m4=*(const float4*)&wredA[t*4];
        float gm=fmaxf(fmaxf(m4.x,m4.y),fmaxf(m4.z,m4.w));
        float e=valid?__expf(scr[t]-gm):0.f;
        ex[t]=e;
        float s=e;
        #pragma unroll
        for(int o=32;o>0;o>>=1) s+=__shfl_xor(s,o,64);
        mx[t]=s;
      }
      if(l==0){
        #pragma unroll
        for(int t=0;t<16;t++) wredB[t*4+w]=mx[t];
      }
      __syncthreads();                             // B3: wredB ready
      #pragma unroll
      for(int t=0;t<16;t++){
        const float4 s4v=*(const float4*)&wredB[t*4];
        float tot=(s4v.x+s4v.y)+(s4v.z+s4v.w);
        ex[t]*=1.0f/tot;                           // att
      }
      if(valid){
        #pragma unroll
        for(int cg=0;cg<4;cg++)
          *(float4*)&sbuf[g*20+4*cg]=make_float4(ex[4*cg+0],ex[4*cg+1],ex[4*cg+2],ex[4*cg+3]);
      }
      __syncthreads();                             // B4: att + hn_s visible
      float r0=0.f,r1=0.f,r2=0.f,r3=0.f;
      #pragma unroll 8
      for(int j=0;j<NKn;j++){
        float4 a4=*(const float4*)&sbuf[j*20+w*4];
        float sv=sbase[(size_t)j*64+l];            // L2-resident, coalesced (VMEM pipe)
        r0=fmaf(a4.x,sv,r0);
        r1=fmaf(a4.y,sv,r1);
        r2=fmaf(a4.z,sv,r2);
        r3=fmaf(a4.w,sv,r3);
      }
      int rb=w*4;
      hu_s[(rb+0)*64+l]=r0 + hn_s[(rb+0)*64+l];
      hu_s[(rb+1)*64+l]=r1 + hn_s[(rb+1)*64+l];
      hu_s[(rb+2)*64+l]=r2 + hn_s[(rb+2)*64+l];
      hu_s[(rb+3)*64+l]=r3 + hn_s[(rb+3)*64+l];
      __syncthreads();                             // B5: hu ready for next iteration
    }
  }
  __syncthreads();                                 // hn_s complete
  float tnorm[16];
  #pragma unroll
  for(int t=0;t<16;t++){
    float v=hn_s[t*64+l];
    float s=v*v;
    #pragma unroll
    for(int o=32;o>0;o>>=1) s+=__shfl_xor(s,o,64);
    tnorm[t]=sqrtf(s);
  }
  #pragma unroll
  for(int t=0;t<16;t++){
    const float4* h4p=(const float4*)&hn_s[t*64];
    float a0=0.f,a1=0.f;
    #pragma unroll
    for(int kc=0;kc<16;kc++){
      float4 h4=h4p[kc];
      a0=fmaf(s4f[4*kc+0],h4.x,a0);
      a1=fmaf(s4f[4*kc+1],h4.y,a1);
      a0=fmaf(s4f[4*kc+2],h4.z,a0);
      a1=fmaf(s4f[4*kc+3],h4.w,a1);
    }
    scr[t]=(a0+a1) / fmaxf(tnorm[t]*snr,1e-8f);
  }
  #pragma unroll
  for(int t=0;t<16;t++){
    float m = valid ? scr[t] : -1e30f;
    #pragma unroll
    for(int o=32;o>0;o>>=1) m=fmaxf(m,__shfl_xor(m,o,64));
    mx[t]=m;
  }
  if(l==0){
    #pragma unroll
    for(int t=0;t<16;t++) wredA[t*4+w]=mx[t];
  }
  __syncthreads();
  #pragma unroll
  for(int t=0;t<16;t++){
    const float4 m4=*(const float4*)&wredA[t*4];
    float gm=fmaxf(fmaxf(m4.x,m4.y),fmaxf(m4.z,m4.w));
    float e=valid?__expf(scr[t]-gm):0.f;
    ex[t]=e;
    float s=e;
    #pragma unroll
    for(int o=32;o>0;o>>=1) s+=__shfl_xor(s,o,64);
    mx[t]=s;
  }
  if(l==0){
    #pragma unroll
    for(int t=0;t<16;t++) wredB[t*4+w]=mx[t];
  }
  __syncthreads();
  #pragma unroll
  for(int t=0;t<16;t++){
    const float4 s4v=*(const float4*)&wredB[t*4];
    float tot=(s4v.x+s4v.y)+(s4v.z+s4v.w);
    if(valid) out[((size_t)(m0+t))*NKn + g]=ex[t]*(1.0f/tot);
  }
}

extern "C" void kernel_launch(void* const* d_in, const int* in_sizes, int n_in,
                              void* d_out, int out_size, void* d_ws, size_t ws_size,
                              hipStream_t stream) {
  (void)in_sizes; (void)n_in; (void)out_size;
  const int*   sup_toks = (const int*)d_in[0];
  const int*   tgt_toks = (const int*)d_in[1];
  const float* emb      = (const float*)d_in[2];
  const float* f_Wih    = (const float*)d_in[3];
  const float* f_Whh    = (const float*)d_in[4];
  const float* f_bih    = (const float*)d_in[5];
  const float* f_bhh    = (const float*)d_in[6];
  const float* gf_Wih   = (const float*)d_in[7];
  const float* gf_Whh   = (const float*)d_in[8];
  const float* gf_bih   = (const float*)d_in[9];
  const float* gf_bhh   = (const float*)d_in[10];
  const float* gb_Wih   = (const float*)d_in[11];
  const float* gb_Whh   = (const float*)d_in[12];
  const float* gb_bih   = (const float*)d_in[13];
  const float* gb_bhh   = (const float*)d_in[14];

  float* ws = (float*)d_ws;
  float* sup_enc = ws;                         // 819200
  float* tgt_enc = sup_enc + 819200;           // 524288
  float* bufA    = tgt_enc + 524288;           // 3276800 : xg_f (fallback: zx after lstm)
  float* bufB    = bufA    + 3276800;          // 3276800 : xg_b
  float* semb    = bufB    + 3276800;          // 819200  : hf, then sup_emb
  float* hb      = semb    + 819200;           // 819200
  float* sn      = hb      + 819200;           // 12800
  float* zxded   = sn      + 12800;            // 2097152 : dedicated zx (fused path only)

  // fused path needs (9548288 + 2097152) floats of workspace
  bool fused = ws_size >= (size_t)(9548288 + 2097152) * sizeof(float);
  float* zx = fused ? zxded : bufA;

  float* xg_f = bufA;
  float* xg_b = bufB;

  gemm_sup2_tgt<<<1312,256,0,stream>>>(sup_toks, emb, sup_enc,
                                       gf_Wih, gb_Wih,
                                       gf_bih, gf_bhh, gb_bih, gb_bhh, xg_f, xg_b,
                                       tgt_toks, tgt_enc);
  if (fused){
    // lstm (blocks 0..127, setprio 1) + zx GEMM (blocks 128..639) on the idle CUs
    lstm_zx<<<640,256,0,stream>>>(xg_f, xg_b, gf_Whh, gb_Whh, semb /*hf*/, hb,
                                  tgt_enc, f_Wih, f_bih, f_bhh, zx);
    combine_norm<<<800,256,0,stream>>>(semb /*hf*/, hb, sup_enc, semb, sn);
  } else {
    lstm_zx<<<128,256,0,stream>>>(xg_f, xg_b, gf_Whh, gb_Whh, semb /*hf*/, hb,
                                  tgt_enc, f_Wih, f_bih, f_bhh, zx);
    gemmz_combine<<<1312,256,0,stream>>>(tgt_enc, f_Wih, f_bih, f_bhh, zx,
                                         semb, hb, sup_enc, semb, sn);
  }
  fused_K<<<512,256,0,stream>>>(zx, f_Whh, tgt_enc, semb, sn, (float*)d_out);
}